// Round 9
// baseline (2558.109 us; speedup 1.0000x reference)
//
#include <hip/hip_runtime.h>
#include <hip/hip_bf16.h>
#include <math.h>

#define Dm 768
#define Tt 1024
#define Bb 2
#define Hh 12
#define DFF 4096
#define Ll 12
#define Vv 50257
#define ROWS (Bb*Tt)   // 2048
#define LN_EPS 1e-5f

typedef unsigned int uint;
typedef unsigned short ushort;
typedef float f32x4 __attribute__((ext_vector_type(4)));
typedef short bf16x8 __attribute__((ext_vector_type(8)));
typedef ushort us8 __attribute__((ext_vector_type(8)));

__device__ __forceinline__ ushort f2bf(float f) {
  uint u = __builtin_bit_cast(uint, f);
  u += 0x7FFFu + ((u >> 16) & 1u);   // RNE
  return (ushort)(u >> 16);
}

__device__ __forceinline__ bf16x8 pack8(f32x4 a, f32x4 b) {
  bf16x8 o;
  o[0] = (short)f2bf(a[0]); o[1] = (short)f2bf(a[1]);
  o[2] = (short)f2bf(a[2]); o[3] = (short)f2bf(a[3]);
  o[4] = (short)f2bf(b[0]); o[5] = (short)f2bf(b[1]);
  o[6] = (short)f2bf(b[2]); o[7] = (short)f2bf(b[3]);
  return o;
}

#define GLL(gp, lp)                                                          \
  __builtin_amdgcn_global_load_lds(                                          \
      (const __attribute__((address_space(1))) uint*)(gp),                   \
      (__attribute__((address_space(3))) uint*)(lp), 16, 0, 0)

// ---------------------------------------------------------------------------
// Fused embedding + LayerNorm: x = tok[idx]+pos (fp32), h = LN(x) (bf16)
// ---------------------------------------------------------------------------
__global__ __launch_bounds__(256) void embed_ln(
    const int* __restrict__ idx, const float* __restrict__ tok,
    const float* __restrict__ pos, const float* __restrict__ w,
    const float* __restrict__ b, float* __restrict__ x,
    ushort* __restrict__ out) {
  const int row = blockIdx.x;
  const int t = row & (Tt - 1);
  const int tid = threadIdx.x;
  const float* tsrc = tok + (size_t)idx[row] * Dm;
  const float* psrc = pos + (size_t)t * Dm;
  float v[3];
  float sum = 0.f, sq = 0.f;
#pragma unroll
  for (int i = 0; i < 3; i++) {
    const int d = tid + i * 256;
    v[i] = tsrc[d] + psrc[d];
    x[(size_t)row * Dm + d] = v[i];
    sum += v[i]; sq += v[i] * v[i];
  }
#pragma unroll
  for (int off = 32; off > 0; off >>= 1) {
    sum += __shfl_xor(sum, off);
    sq  += __shfl_xor(sq, off);
  }
  __shared__ float red[8];
  const int wid = tid >> 6, lane = tid & 63;
  if (lane == 0) { red[wid] = sum; red[wid + 4] = sq; }
  __syncthreads();
  sum = red[0] + red[1] + red[2] + red[3];
  sq  = red[4] + red[5] + red[6] + red[7];
  const float mu = sum * (1.f / Dm);
  const float var = sq * (1.f / Dm) - mu * mu;
  const float rstd = rsqrtf(var + LN_EPS);
  ushort* dst = out + (size_t)row * Dm;
#pragma unroll
  for (int i = 0; i < 3; i++) {
    const int d = tid + i * 256;
    dst[d] = f2bf((v[i] - mu) * rstd * w[d] + b[d]);
  }
}

// ---------------------------------------------------------------------------
// Fused split-K reduce + bias + residual (x += ...) + LayerNorm -> bf16 h
// ---------------------------------------------------------------------------
__global__ __launch_bounds__(256) void red_ln(
    const float* __restrict__ part, int nsk, const float* __restrict__ bias,
    float* __restrict__ x, const float* __restrict__ w,
    const float* __restrict__ b, ushort* __restrict__ out) {
  const int row = blockIdx.x;
  const int tid = threadIdx.x;
  float v[3];
  float sum = 0.f, sq = 0.f;
#pragma unroll
  for (int i = 0; i < 3; i++) {
    const int d = tid + i * 256;
    const size_t off = (size_t)row * Dm + d;
    float s = x[off] + bias[d];
    for (int k = 0; k < nsk; k++) s += part[(size_t)k * ROWS * Dm + off];
    x[off] = s;
    v[i] = s;
    sum += s; sq += s * s;
  }
#pragma unroll
  for (int off = 32; off > 0; off >>= 1) {
    sum += __shfl_xor(sum, off);
    sq  += __shfl_xor(sq, off);
  }
  __shared__ float red[8];
  const int wid = tid >> 6, lane = tid & 63;
  if (lane == 0) { red[wid] = sum; red[wid + 4] = sq; }
  __syncthreads();
  sum = red[0] + red[1] + red[2] + red[3];
  sq  = red[4] + red[5] + red[6] + red[7];
  const float mu = sum * (1.f / Dm);
  const float var = sq * (1.f / Dm) - mu * mu;
  const float rstd = rsqrtf(var + LN_EPS);
  ushort* dst = out + (size_t)row * Dm;
#pragma unroll
  for (int i = 0; i < 3; i++) {
    const int d = tid + i * 256;
    dst[d] = f2bf((v[i] - mu) * rstd * w[d] + b[d]);
  }
}

// ---------------------------------------------------------------------------
// Weight converter fp32 -> bf16 (head only now)
// ---------------------------------------------------------------------------
__global__ __launch_bounds__(256) void convert_w(
    const float* __restrict__ s, ushort* __restrict__ d, int n4) {
  const int stride = gridDim.x * 256;
  for (int i = blockIdx.x * 256 + threadIdx.x; i < n4; i += stride) {
    const float4 v = ((const float4*)s)[i];
    ushort4 o;
    o.x = f2bf(v.x); o.y = f2bf(v.y); o.z = f2bf(v.z); o.w = f2bf(v.w);
    ((ushort4*)d)[i] = o;
  }
}

// ---------------------------------------------------------------------------
// bf16 MFMA GEMM (loop GEMMs): C[M,Nloc] = A(bf16)[M,*]@B(FP32)[N,*]^T + epi.
// B is read fp32 from the ORIGINAL weights and converted during reg-staging:
// global_load_dwordx4 (2 tiles ahead) -> f2bf pack -> ds_write_b128 into the
// same swizzled bf16 LDS layout as before (read side unchanged).
// ---------------------------------------------------------------------------
#define EPI_QKV 0
#define EPI_PART 1
#define EPI_BIAS_GELU 2
#define EPI_NONE 3

template <int EPI>
__global__ __launch_bounds__(256) void gemm_mfma(
    const ushort* __restrict__ A, const float* __restrict__ Bf,
    const float* __restrict__ bias, void* __restrict__ Cv,
    void* __restrict__ Cv2, int Kloop, int Kstr, int Nloc, int ldC) {
  __shared__ char lds[32768];           // 2 x (A 8KB + B 8KB)
  const int tid = threadIdx.x;
  const int l = tid & 63;
  const int wid = __builtin_amdgcn_readfirstlane(tid >> 6);
  const int wr = wid >> 1, wc = wid & 1;
  const int m0 = blockIdx.y * 128;
  const int n0 = blockIdx.x * 128;
  const int z = (EPI == EPI_PART) ? blockIdx.z : 0;
  if (EPI == EPI_PART) { A += (size_t)z * Kloop; Bf += (size_t)z * Kloop; }

  // A staging via global_load_lds (source chunk pre-swizzled)
  const int cperm = (((l & 3) ^ ((l >> 3) & 3)) * 8);
  const ushort* gA = A + (size_t)(m0 + wid * 32 + (l >> 2)) * Kstr + cperm;

  // B reg-staging: chunks c0=tid, c1=tid+256; row=c>>2, slot=c&3,
  // LDS slot s of row r holds logical chunk q = s ^ ((r>>1)&3).
  const int r0 = tid >> 2, s0 = tid & 3;
  const int q0 = s0 ^ ((r0 >> 1) & 3);         // same q for r0 and r0+64
  const float* gB0 = Bf + (size_t)(n0 + r0) * Kstr + q0 * 8;
  const float* gB1 = Bf + (size_t)(n0 + r0 + 64) * Kstr + q0 * 8;
  const int wOff0 = 8192 + r0 * 64 + s0 * 16;
  const int wOff1 = 8192 + (r0 + 64) * 64 + s0 * 16;

  const int rdSw = (l & 15) * 64 + (((l >> 4) ^ ((l >> 1) & 3)) * 16);
  const int aRd = wr * 4096 + rdSw;
  const int bRd = 8192 + wc * 4096 + rdSw;

  f32x4 acc[4][4] = {};
  const int nt = Kloop / 32;

  // prologue: B(0) -> regs -> LDS buf0; A(0) via GLL; B(1) -> regs
  f32x4 rb0, rb1, rb2, rb3;
  rb0 = *(const f32x4*)(gB0);     rb1 = *(const f32x4*)(gB0 + 4);
  rb2 = *(const f32x4*)(gB1);     rb3 = *(const f32x4*)(gB1 + 4);
  *(bf16x8*)(lds + wOff0) = pack8(rb0, rb1);
  *(bf16x8*)(lds + wOff1) = pack8(rb2, rb3);
  {
    const int lb = wid * 2048;
    GLL(gA, lds + lb);  GLL(gA + 16 * Kstr, lds + lb + 1024);
  }
  rb0 = *(const f32x4*)(gB0 + 32); rb1 = *(const f32x4*)(gB0 + 36);
  rb2 = *(const f32x4*)(gB1 + 32); rb3 = *(const f32x4*)(gB1 + 36);

  for (int t = 0; t < nt; ++t) {
    __syncthreads();                   // tile t fully resident in buf t&1
    if (t + 1 < nt) {                  // write B(t+1) (regs), stage A(t+1)
      char* bb = lds + ((t + 1) & 1) * 16384;
      *(bf16x8*)(bb + wOff0) = pack8(rb0, rb1);
      *(bf16x8*)(bb + wOff1) = pack8(rb2, rb3);
      const int lb = ((t + 1) & 1) * 16384 + wid * 2048;
      const ushort* a = gA + (t + 1) * 32;
      GLL(a, lds + lb);  GLL(a + 16 * Kstr, lds + lb + 1024);
    }
    if (t + 2 < nt) {                  // issue B(t+2) loads early
      const int o = (t + 2) * 32;
      rb0 = *(const f32x4*)(gB0 + o);      rb1 = *(const f32x4*)(gB0 + o + 4);
      rb2 = *(const f32x4*)(gB1 + o);      rb3 = *(const f32x4*)(gB1 + o + 4);
    }
    const int base = (t & 1) * 16384;
    bf16x8 av[4], bv[4];
#pragma unroll
    for (int i = 0; i < 4; ++i) {
      av[i] = *(const bf16x8*)(lds + base + aRd + i * 1024);
      bv[i] = *(const bf16x8*)(lds + base + bRd + i * 1024);
    }
#pragma unroll
    for (int i = 0; i < 4; ++i)
#pragma unroll
      for (int j = 0; j < 4; ++j)
        acc[i][j] = __builtin_amdgcn_mfma_f32_16x16x32_bf16(
            av[i], bv[j], acc[i][j], 0, 0, 0);
  }

#pragma unroll
  for (int fm = 0; fm < 4; ++fm) {
    const int row0 = m0 + wr * 64 + fm * 16 + (l >> 4) * 4;
#pragma unroll
    for (int fn = 0; fn < 4; ++fn) {
      const int col = n0 + wc * 64 + fn * 16 + (l & 15);
      if (col >= Nloc) continue;
      float bi = 0.f;
      if (EPI == EPI_QKV || EPI == EPI_BIAS_GELU) bi = bias[col];
      if (EPI == EPI_QKV && col >= 2 * Dm) {
        const int hh = (col - 2 * Dm) >> 6, dd = col & 63;
        const int bI = row0 >> 10, t0 = row0 & (Tt - 1);
        ushort4 o4;
        o4.x = f2bf(acc[fm][fn][0] + bi);
        o4.y = f2bf(acc[fm][fn][1] + bi);
        o4.z = f2bf(acc[fm][fn][2] + bi);
        o4.w = f2bf(acc[fm][fn][3] + bi);
        *(ushort4*)((ushort*)Cv2 +
                    ((size_t)((bI * Hh + hh) * 64 + dd)) * Tt + t0) = o4;
        continue;
      }
#pragma unroll
      for (int r = 0; r < 4; ++r) {
        float v = acc[fm][fn][r] + bi;
        const size_t off = (size_t)(row0 + r) * ldC + col;
        if (EPI == EPI_BIAS_GELU) {
          v = 0.5f * v * (1.f + erff(v * 0.70710678118654752f));
          ((ushort*)Cv)[off] = f2bf(v);
        } else if (EPI == EPI_QKV) {
          ((ushort*)Cv)[off] = f2bf(v);
        } else if (EPI == EPI_PART) {
          ((float*)Cv)[(size_t)z * ROWS * ldC + off] = v;
        } else {
          ((float*)Cv)[off] = v;
        }
      }
    }
  }
}

// ---------------------------------------------------------------------------
// Head GEMM (unchanged from R8): 256x256, 4 LDS bufs, counted vmcnt,
// conflict-free (r>>1)&3 swizzle, XCD panel-major mapping.
// ---------------------------------------------------------------------------
__global__ __launch_bounds__(512, 2) void gemm_head8(
    const ushort* __restrict__ A, const ushort* __restrict__ B,
    float* __restrict__ C) {
  __shared__ char lds[131072];
  const int tid = threadIdx.x;
  const int l = tid & 63;
  const int wid = __builtin_amdgcn_readfirstlane(tid >> 6);
  const int wm = wid >> 2, wn = wid & 3;

  const int bid = blockIdx.x;
  const int swz = (bid & 7) * 197 + (bid >> 3);
  const int pan = swz >> 3, mrw = swz & 7;
  const int m0 = mrw * 256;
  const int n0 = pan * 256;

  const ushort* gA[2];
  const ushort* gB[2];
#pragma unroll
  for (int j = 0; j < 2; j++) {
    const int c = tid + j * 512;
    const int r = c >> 2, kq = c & 3;
    gA[j] = A + (size_t)(m0 + r) * Dm + ((kq ^ ((r >> 1) & 3)) * 8);
    int rb = n0 + r;
    rb = min(rb, Vv - 1);
    gB[j] = B + (size_t)rb * Dm + ((kq ^ ((r >> 1) & 3)) * 8);
  }

#define HSTAGE(t)                                                            \
  do {                                                                       \
    char* _lb = lds + ((t) & 3) * 32768;                                     \
    const int _o = (t) * 32;                                                 \
    GLL(gA[0] + _o, _lb + tid * 16);                                         \
    GLL(gA[1] + _o, _lb + 8192 + tid * 16);                                  \
    GLL(gB[0] + _o, _lb + 16384 + tid * 16);                                 \
    GLL(gB[1] + _o, _lb + 24576 + tid * 16);                                 \
  } while (0)

  f32x4 acc[8][4] = {};
  const int s = l & 15, g = l >> 4;

  int aOff[8], bOff[4];
#pragma unroll
  for (int fm = 0; fm < 8; fm++) {
    const int r = wm * 128 + fm * 16 + s;
    aOff[fm] = r * 64 + ((g ^ ((r >> 1) & 3)) * 16);
  }
#pragma unroll
  for (int fn = 0; fn < 4; fn++) {
    const int r = wn * 64 + fn * 16 + s;
    bOff[fn] = 16384 + r * 64 + ((g ^ ((r >> 1) & 3)) * 16);
  }

  HSTAGE(0); HSTAGE(1); HSTAGE(2);
  asm volatile("s_waitcnt vmcnt(8)" ::: "memory");
  __builtin_amdgcn_s_barrier();
  __builtin_amdgcn_sched_barrier(0);

#define HITER(t, VC)                                                         \
  {                                                                          \
    if ((t) + 3 < 24) HSTAGE((t) + 3);                                       \
    char* bb = lds + ((t) & 3) * 32768;                                      \
    bf16x8 av[8], bv[4];                                                     \
    _Pragma("unroll")                                                        \
    for (int fm = 0; fm < 8; fm++) av[fm] = *(const bf16x8*)(bb + aOff[fm]); \
    _Pragma("unroll")                                                        \
    for (int fn = 0; fn < 4; fn++) bv[fn] = *(const bf16x8*)(bb + bOff[fn]); \
    __builtin_amdgcn_s_setprio(1);                                           \
    _Pragma("unroll")                                                        \
    for (int fm = 0; fm < 8; fm++)                                           \
      _Pragma("unroll")                                                      \
      for (int fn = 0; fn < 4; fn++)                                         \
        acc[fm][fn] = __builtin_amdgcn_mfma_f32_16x16x32_bf16(               \
            av[fm], bv[fn], acc[fm][fn], 0, 0, 0);                           \
    __builtin_amdgcn_s_setprio(0);                                           \
    asm volatile("s_waitcnt lgkmcnt(0)" ::: "memory");                       \
    asm volatile("s_waitcnt vmcnt(" #VC ")" ::: "memory");                   \
    __builtin_amdgcn_s_barrier();                                            \
    __builtin_amdgcn_sched_barrier(0);                                       \
  }

#pragma unroll 1
  for (int t = 0; t <= 20; ++t) HITER(t, 8);
  HITER(21, 4);
  HITER(22, 0);
  HITER(23, 0);

#pragma unroll
  for (int fm = 0; fm < 8; ++fm) {
    const int row0 = m0 + wm * 128 + fm * 16 + g * 4;
#pragma unroll
    for (int fn = 0; fn < 4; ++fn) {
      const int col = n0 + wn * 64 + fn * 16 + s;
      if (col >= Vv) continue;
#pragma unroll
      for (int r = 0; r < 4; ++r)
        C[(size_t)(row0 + r) * Vv + col] = acc[fm][fn][r];
    }
  }
}

// ---------------------------------------------------------------------------
// MFMA flash attention (unchanged).
// ---------------------------------------------------------------------------
__global__ __launch_bounds__(128) void attn_mfma(
    const ushort* __restrict__ qkv, const ushort* __restrict__ vTg,
    ushort* __restrict__ y) {
  __shared__ char lds[36864];
  const int tid = threadIdx.x;
  const int l = tid & 63;
  const int w = tid >> 6;
  const int s = l & 15, g = l >> 4;
  const int bq = gridDim.x - 1 - blockIdx.x;
  const int h = blockIdx.y, b = blockIdx.z;
  const int bh = b * Hh + h;

  const int qrow = bq * 32 + w * 16 + s;
  const ushort* qp = qkv + (size_t)(b * Tt + qrow) * 2304 + h * 64 + g * 8;
  const bf16x8 aq0 = *(const bf16x8*)qp;
  const bf16x8 aq1 = *(const bf16x8*)(qp + 32);

  size_t gofs[8];
#pragma unroll
  for (int i = 0; i < 8; i++) {
    const int c = tid + i * 128;
    if (i < 4) {
      const int kr = c >> 3;
      gofs[i] = (size_t)(b * Tt + kr) * 2304 + Dm + h * 64 + ((c & 7) ^ (kr & 7)) * 8;
    } else {
      const int cv = c - 512;
      const int vr = cv >> 3;
      gofs[i] = (size_t)(bh * 64 + vr) * Tt + ((cv & 7) ^ (vr & 7)) * 8;
    }
  }

#define ASTAGE(kt, base)                                                     \
  do {                                                                       \
    _Pragma("unroll")                                                        \
    for (int i = 0; i < 8; i++) {                                            \
      const ushort* p = (i < 4) ? (qkv + gofs[i] + (size_t)(kt) * 147456)    \
                                : (vTg + gofs[i] + (kt) * 64);               \
      GLL(p, lds + (base) + tid * 16 + i * 2048);                            \
    }                                                                        \
  } while (0)

  f32x4 oc[4] = {};
  float mrun[4], lrun[4];
#pragma unroll
  for (int r = 0; r < 4; r++) { mrun[r] = -INFINITY; lrun[r] = 0.f; }

  const int pB = 32768 + w * 2048;
  const int kSw = (s & 7);
  const int nkt = (bq >> 1) + 1;

  ASTAGE(0, 0);
  for (int kt = 0; kt < nkt; ++kt) {
    __syncthreads();
    if (kt + 1 < nkt) ASTAGE(kt + 1, ((kt + 1) & 1) * 16384);
    const int cur = (kt & 1) * 16384;

    f32x4 sc[4];
    __builtin_amdgcn_s_setprio(1);
#pragma unroll
    for (int jn = 0; jn < 4; jn++) {
      const int krow = cur + (jn * 16 + s) * 128;
      const bf16x8 bk0 = *(const bf16x8*)(lds + krow + ((g ^ kSw) * 16));
      const bf16x8 bk1 = *(const bf16x8*)(lds + krow + (((4 + g) ^ kSw) * 16));
      f32x4 z = {};
      z = __builtin_amdgcn_mfma_f32_16x16x32_bf16(aq0, bk0, z, 0, 0, 0);
      z = __builtin_amdgcn_mfma_f32_16x16x32_bf16(aq1, bk1, z, 0, 0, 0);
      sc[jn] = z;
    }
    __builtin_amdgcn_s_setprio(0);

    float cr[4];
    const bool diag = (kt == nkt - 1);
#pragma unroll
    for (int r = 0; r < 4; r++) {
      const int rowg = bq * 32 + w * 16 + g * 4 + r;
      float v[4];
#pragma unroll
      for (int jn = 0; jn < 4; jn++) {
        v[jn] = sc[jn][r] * 0.125f;
        if (diag && (kt * 64 + jn * 16 + s) > rowg) v[jn] = -INFINITY;
      }
      float mx = fmaxf(fmaxf(v[0], v[1]), fmaxf(v[2], v[3]));
      mx = fmaxf(mx, __shfl_xor(mx, 1));
      mx = fmaxf(mx, __shfl_xor(mx, 2));
      mx = fmaxf(mx, __shfl_xor(mx, 4));
      mx = fmaxf(mx, __shfl_xor(mx, 8));
      const float mnew = fmaxf(mrun[r], mx);
      const float corr = __expf(mrun[r] - mnew);
      mrun[r] = mnew;
      float ps = 0.f;
#pragma unroll
      for (int jn = 0; jn < 4; jn++) {
        const float p = __expf(v[jn] - mnew);
        ps += p;
        *(ushort*)(lds + pB + (g * 4 + r) * 128 +
                   (((2 * jn + (s >> 3)) ^ g) * 16) + (s & 7) * 2) = f2bf(p);
      }
      ps += __shfl_xor(ps, 1);
      ps += __shfl_xor(ps, 2);
      ps += __shfl_xor(ps, 4);
      ps += __shfl_xor(ps, 8);
      lrun[r] = lrun[r] * corr + ps;
      cr[r] = corr;
    }

    const float c01 = (s & 1) ? cr[1] : cr[0];
    const float c23 = (s & 1) ? cr[3] : cr[2];
    const float csel = (s & 2) ? c23 : c01;
    const float ccol = __shfl(csel, ((s >> 2) << 4) | s);
#pragma unroll
    for (int fm = 0; fm < 4; fm++) {
      oc[fm][0] *= ccol; oc[fm][1] *= ccol;
      oc[fm][2] *= ccol; oc[fm][3] *= ccol;
    }

    const bf16x8 bp0 = *(const bf16x8*)(lds + pB + s * 128 + ((g ^ (s >> 2)) * 16));
    const bf16x8 bp1 = *(const bf16x8*)(lds + pB + s * 128 + (((4 + g) ^ (s >> 2)) * 16));
    __builtin_amdgcn_s_setprio(1);
#pragma unroll
    for (int fm = 0; fm < 4; fm++) {
      const int vrow = cur + 8192 + (fm * 16 + s) * 128;
      const bf16x8 av0 = *(const bf16x8*)(lds + vrow + ((g ^ kSw) * 16));
      const bf16x8 av1 = *(const bf16x8*)(lds + vrow + (((4 + g) ^ kSw) * 16));
      oc[fm] = __builtin_amdgcn_mfma_f32_16x16x32_bf16(av0, bp0, oc[fm], 0, 0, 0);
      oc[fm] = __builtin_amdgcn_mfma_f32_16x16x32_bf16(av1, bp1, oc[fm], 0, 0, 0);
    }
    __builtin_amdgcn_s_setprio(0);
  }

  float li[4];
#pragma unroll
  for (int r = 0; r < 4; r++) li[r] = 1.f / lrun[r];
  const float l01 = (s & 1) ? li[1] : li[0];
  const float l23 = (s & 1) ? li[3] : li[2];
  const float lsel = (s & 2) ? l23 : l01;
  const float lcol = __shfl(lsel, ((s >> 2) << 4) | s);
  ushort* yp = y + (size_t)(b * Tt + qrow) * Dm + h * 64;
#pragma unroll
  for (int fm = 0; fm < 4; fm++) {
    ushort4 o4;
    o4.x = f2bf(oc[fm][0] * lcol);
    o4.y = f2bf(oc[fm][1] * lcol);
    o4.z = f2bf(oc[fm][2] * lcol);
    o4.w = f2bf(oc[fm][3] * lcol);
    *(ushort4*)(yp + fm * 16 + g * 4) = o4;
  }
}

// ---------------------------------------------------------------------------
extern "C" void kernel_launch(void* const* d_in, const int* in_sizes, int n_in,
                              void* d_out, int out_size, void* d_ws, size_t ws_size,
                              hipStream_t stream) {
  const int* idx = (const int*)d_in[0];
  const float* tok = (const float*)d_in[1];
  const float* pos = (const float*)d_in[2];
  const float* ln1w = (const float*)d_in[3];
  const float* ln1b = (const float*)d_in[4];
  const float* qkvw = (const float*)d_in[5];
  const float* qkvb = (const float*)d_in[6];
  const float* projw = (const float*)d_in[7];
  const float* projb = (const float*)d_in[8];
  const float* ln2w = (const float*)d_in[9];
  const float* ln2b = (const float*)d_in[10];
  const float* ff1w = (const float*)d_in[11];
  const float* ff1b = (const float*)d_in[12];
  const float* ff2w = (const float*)d_in[13];
  const float* ff2b = (const float*)d_in[14];
  const float* lnfw = (const float*)d_in[15];
  const float* lnfb = (const float*)d_in[16];
  const float* headw = (const float*)d_in[17];
  float* out = (float*)d_out;

  char* ws = (char*)d_ws;
  ushort* h    = (ushort*)ws;                    // [2048][768] bf16
  float*  x    = (float*)(ws + 3145728);         // [2048][768] fp32
  ushort* y    = (ushort*)(ws + 9437184);        // [2048][768] bf16
  ushort* qkv  = (ushort*)(ws + 12582912);       // [2048][2304] bf16
  ushort* vTg  = (ushort*)(ws + 22020096);       // [24][64][1024] bf16
  ushort* ff   = (ushort*)(ws + 25165824);       // [2048][4096] bf16
  ushort* wb   = (ushort*)(ws + 41943040);       // head weights bf16 (77MB)
  float* projPart = (float*)(ws + 12582912);     // 2x6.29MB over qkv+vT
  float* ff2Part  = (float*)(ws + 9437184);      // 2x6.29MB over y+qkv

  convert_w<<<2048, 256, 0, stream>>>(headw, wb, (int)((size_t)Vv * Dm / 4));

  embed_ln<<<ROWS, 256, 0, stream>>>(idx, tok, pos, ln1w, ln1b, x, h);

  for (int l = 0; l < Ll; l++) {
    gemm_mfma<EPI_QKV><<<dim3(18, 16), 256, 0, stream>>>(
        h, qkvw + (size_t)l * 3 * Dm * Dm, qkvb + l * 3 * Dm, qkv, vTg,
        Dm, Dm, 3 * Dm, 3 * Dm);
    attn_mfma<<<dim3(32, Hh, Bb), 128, 0, stream>>>(qkv, vTg, y);
    gemm_mfma<EPI_PART><<<dim3(6, 16, 2), 256, 0, stream>>>(
        y, projw + (size_t)l * Dm * Dm, nullptr, projPart, nullptr,
        Dm / 2, Dm, Dm, Dm);
    red_ln<<<ROWS, 256, 0, stream>>>(projPart, 2, projb + l * Dm, x,
                                     ln2w + l * Dm, ln2b + l * Dm, h);
    gemm_mfma<EPI_BIAS_GELU><<<dim3(32, 16), 256, 0, stream>>>(
        h, ff1w + (size_t)l * DFF * Dm, ff1b + l * DFF, ff, nullptr,
        Dm, Dm, DFF, DFF);
    gemm_mfma<EPI_PART><<<dim3(6, 16, 2), 256, 0, stream>>>(
        ff, ff2w + (size_t)l * Dm * DFF, nullptr, ff2Part, nullptr,
        DFF / 2, DFF, Dm, Dm);
    const float* nw = (l == Ll - 1) ? lnfw : ln1w + (l + 1) * Dm;
    const float* nb = (l == Ll - 1) ? lnfb : ln1b + (l + 1) * Dm;
    red_ln<<<ROWS, 256, 0, stream>>>(ff2Part, 2, ff2b + l * Dm, x, nw, nb, h);
  }

  gemm_head8<<<1576, 512, 0, stream>>>(h, wb, out);
}

// Round 10
// 2194.569 us; speedup vs baseline: 1.1657x; 1.1657x over previous
//
#include <hip/hip_runtime.h>
#include <hip/hip_bf16.h>
#include <math.h>

#define Dm 768
#define Tt 1024
#define Bb 2
#define Hh 12
#define DFF 4096
#define Ll 12
#define Vv 50257
#define ROWS (Bb*Tt)   // 2048
#define LN_EPS 1e-5f

typedef unsigned int uint;
typedef unsigned short ushort;
typedef float f32x4 __attribute__((ext_vector_type(4)));
typedef short bf16x8 __attribute__((ext_vector_type(8)));
typedef ushort us8 __attribute__((ext_vector_type(8)));

__device__ __forceinline__ ushort f2bf(float f) {
  uint u = __builtin_bit_cast(uint, f);
  u += 0x7FFFu + ((u >> 16) & 1u);   // RNE
  return (ushort)(u >> 16);
}

#define GLL(gp, lp)                                                          \
  __builtin_amdgcn_global_load_lds(                                          \
      (const __attribute__((address_space(1))) uint*)(gp),                   \
      (__attribute__((address_space(3))) uint*)(lp), 16, 0, 0)

// ---------------------------------------------------------------------------
// Fused embedding + LayerNorm: x = tok[idx]+pos (fp32), h = LN(x) (bf16)
// ---------------------------------------------------------------------------
__global__ __launch_bounds__(256) void embed_ln(
    const int* __restrict__ idx, const float* __restrict__ tok,
    const float* __restrict__ pos, const float* __restrict__ w,
    const float* __restrict__ b, float* __restrict__ x,
    ushort* __restrict__ out) {
  const int row = blockIdx.x;
  const int t = row & (Tt - 1);
  const int tid = threadIdx.x;
  const float* tsrc = tok + (size_t)idx[row] * Dm;
  const float* psrc = pos + (size_t)t * Dm;
  float v[3];
  float sum = 0.f, sq = 0.f;
#pragma unroll
  for (int i = 0; i < 3; i++) {
    const int d = tid + i * 256;
    v[i] = tsrc[d] + psrc[d];
    x[(size_t)row * Dm + d] = v[i];
    sum += v[i]; sq += v[i] * v[i];
  }
#pragma unroll
  for (int off = 32; off > 0; off >>= 1) {
    sum += __shfl_xor(sum, off);
    sq  += __shfl_xor(sq, off);
  }
  __shared__ float red[8];
  const int wid = tid >> 6, lane = tid & 63;
  if (lane == 0) { red[wid] = sum; red[wid + 4] = sq; }
  __syncthreads();
  sum = red[0] + red[1] + red[2] + red[3];
  sq  = red[4] + red[5] + red[6] + red[7];
  const float mu = sum * (1.f / Dm);
  const float var = sq * (1.f / Dm) - mu * mu;
  const float rstd = rsqrtf(var + LN_EPS);
  ushort* dst = out + (size_t)row * Dm;
#pragma unroll
  for (int i = 0; i < 3; i++) {
    const int d = tid + i * 256;
    dst[d] = f2bf((v[i] - mu) * rstd * w[d] + b[d]);
  }
}

// ---------------------------------------------------------------------------
// Fused split-K reduce + bias + residual + LayerNorm -> bf16 h
// 192 threads, float4 per thread (768 = 192*4).
// ---------------------------------------------------------------------------
__global__ __launch_bounds__(192) void red_ln(
    const float* __restrict__ part, int nsk, const float* __restrict__ bias,
    float* __restrict__ x, const float* __restrict__ w,
    const float* __restrict__ b, ushort* __restrict__ out) {
  const int row = blockIdx.x;
  const int tid = threadIdx.x;
  const size_t o4 = (size_t)row * 192 + tid;
  float4 xv = ((const float4*)x)[o4];
  const float4 b4 = ((const float4*)bias)[tid];
  xv.x += b4.x; xv.y += b4.y; xv.z += b4.z; xv.w += b4.w;
  for (int k = 0; k < nsk; k++) {
    const float4 p = ((const float4*)part)[(size_t)k * ROWS * 192 + o4];
    xv.x += p.x; xv.y += p.y; xv.z += p.z; xv.w += p.w;
  }
  ((float4*)x)[o4] = xv;
  float sum = xv.x + xv.y + xv.z + xv.w;
  float sq = xv.x * xv.x + xv.y * xv.y + xv.z * xv.z + xv.w * xv.w;
#pragma unroll
  for (int off = 32; off > 0; off >>= 1) {
    sum += __shfl_xor(sum, off);
    sq  += __shfl_xor(sq, off);
  }
  __shared__ float red[6];
  const int wid = tid >> 6, lane = tid & 63;
  if (lane == 0) { red[wid] = sum; red[wid + 3] = sq; }
  __syncthreads();
  sum = red[0] + red[1] + red[2];
  sq  = red[3] + red[4] + red[5];
  const float mu = sum * (1.f / Dm);
  const float var = sq * (1.f / Dm) - mu * mu;
  const float rstd = rsqrtf(var + LN_EPS);
  const float4 w4 = ((const float4*)w)[tid];
  const float4 bb4 = ((const float4*)b)[tid];
  ushort4 o;
  o.x = f2bf((xv.x - mu) * rstd * w4.x + bb4.x);
  o.y = f2bf((xv.y - mu) * rstd * w4.y + bb4.y);
  o.z = f2bf((xv.z - mu) * rstd * w4.z + bb4.z);
  o.w = f2bf((xv.w - mu) * rstd * w4.w + bb4.w);
  ((ushort4*)out)[o4] = o;
}

// ---------------------------------------------------------------------------
// Weight converter fp32 -> bf16 (count in float4 units, contiguous)
// ---------------------------------------------------------------------------
__global__ __launch_bounds__(256) void convert_w(
    const float* __restrict__ s, ushort* __restrict__ d, int n4) {
  const int stride = gridDim.x * 256;
  for (int i = blockIdx.x * 256 + threadIdx.x; i < n4; i += stride) {
    const float4 v = ((const float4*)s)[i];
    ushort4 o;
    o.x = f2bf(v.x); o.y = f2bf(v.y); o.z = f2bf(v.z); o.w = f2bf(v.w);
    ((ushort4*)d)[i] = o;
  }
}

// ---------------------------------------------------------------------------
// bf16 MFMA GEMM (loop GEMMs): C[M,Nloc] = A[M,*]@B[N,*]^T + epi.
// EPI_PART: blockIdx.z = split-k index (nsk from gridDim.z).
// ---------------------------------------------------------------------------
#define EPI_QKV 0
#define EPI_PART 1
#define EPI_BIAS_GELU 2
#define EPI_NONE 3

template <int EPI>
__global__ __launch_bounds__(256) void gemm_mfma(
    const ushort* __restrict__ A, const ushort* __restrict__ B,
    const float* __restrict__ bias, void* __restrict__ Cv,
    void* __restrict__ Cv2, int Kloop, int Kstr, int Nloc, int ldC) {
  __shared__ char lds[32768];           // 2 x (A 8KB + B 8KB)
  const int tid = threadIdx.x;
  const int l = tid & 63;
  const int wid = __builtin_amdgcn_readfirstlane(tid >> 6);
  const int wr = wid >> 1, wc = wid & 1;
  const int m0 = blockIdx.y * 128;
  const int n0 = blockIdx.x * 128;
  const int z = (EPI == EPI_PART) ? blockIdx.z : 0;
  if (EPI == EPI_PART) { A += (size_t)z * Kloop; B += (size_t)z * Kloop; }

  const int cperm = (((l & 3) ^ ((l >> 3) & 3)) * 8);
  const ushort* gA = A + (size_t)(m0 + wid * 32 + (l >> 2)) * Kstr + cperm;
  int rB = n0 + wid * 32 + (l >> 2);
  rB = min(rB, Nloc - 1);
  const ushort* gB = B + (size_t)rB * Kstr + cperm;

  const int rdSw = (l & 15) * 64 + (((l >> 4) ^ ((l >> 1) & 3)) * 16);
  const int aRd = wr * 4096 + rdSw;
  const int bRd = 8192 + wc * 4096 + rdSw;

  f32x4 acc[4][4] = {};
  const int nt = Kloop / 32;

  {
    const int lb = wid * 2048;
    GLL(gA, lds + lb);          GLL(gA + 16 * Kstr, lds + lb + 1024);
    GLL(gB, lds + 8192 + lb);   GLL(gB + 16 * Kstr, lds + 8192 + lb + 1024);
  }

  for (int t = 0; t < nt; ++t) {
    __syncthreads();
    if (t + 1 < nt) {
      const int base = ((t + 1) & 1) * 16384;
      const int lb = base + wid * 2048;
      const ushort* a = gA + (t + 1) * 32;
      const ushort* b = gB + (t + 1) * 32;
      GLL(a, lds + lb);         GLL(a + 16 * Kstr, lds + lb + 1024);
      GLL(b, lds + 8192 + lb);  GLL(b + 16 * Kstr, lds + 8192 + lb + 1024);
    }
    const int base = (t & 1) * 16384;
    bf16x8 av[4], bv[4];
#pragma unroll
    for (int i = 0; i < 4; ++i) {
      av[i] = *(const bf16x8*)(lds + base + aRd + i * 1024);
      bv[i] = *(const bf16x8*)(lds + base + bRd + i * 1024);
    }
#pragma unroll
    for (int i = 0; i < 4; ++i)
#pragma unroll
      for (int j = 0; j < 4; ++j)
        acc[i][j] = __builtin_amdgcn_mfma_f32_16x16x32_bf16(
            av[i], bv[j], acc[i][j], 0, 0, 0);
  }

#pragma unroll
  for (int fm = 0; fm < 4; ++fm) {
    const int row0 = m0 + wr * 64 + fm * 16 + (l >> 4) * 4;
#pragma unroll
    for (int fn = 0; fn < 4; ++fn) {
      const int col = n0 + wc * 64 + fn * 16 + (l & 15);
      if (col >= Nloc) continue;
      float bi = 0.f;
      if (EPI == EPI_QKV || EPI == EPI_BIAS_GELU) bi = bias[col];
      if (EPI == EPI_QKV && col >= 2 * Dm) {
        const int hh = (col - 2 * Dm) >> 6, dd = col & 63;
        const int bI = row0 >> 10, t0 = row0 & (Tt - 1);
        ushort4 o4;
        o4.x = f2bf(acc[fm][fn][0] + bi);
        o4.y = f2bf(acc[fm][fn][1] + bi);
        o4.z = f2bf(acc[fm][fn][2] + bi);
        o4.w = f2bf(acc[fm][fn][3] + bi);
        *(ushort4*)((ushort*)Cv2 +
                    ((size_t)((bI * Hh + hh) * 64 + dd)) * Tt + t0) = o4;
        continue;
      }
#pragma unroll
      for (int r = 0; r < 4; ++r) {
        float v = acc[fm][fn][r] + bi;
        const size_t off = (size_t)(row0 + r) * ldC + col;
        if (EPI == EPI_BIAS_GELU) {
          v = 0.5f * v * (1.f + erff(v * 0.70710678118654752f));
          ((ushort*)Cv)[off] = f2bf(v);
        } else if (EPI == EPI_QKV) {
          ((ushort*)Cv)[off] = f2bf(v);
        } else if (EPI == EPI_PART) {
          ((float*)Cv)[(size_t)z * ROWS * ldC + off] = v;
        } else {
          ((float*)Cv)[off] = v;
        }
      }
    }
  }
}

// ---------------------------------------------------------------------------
// Head GEMM (R8): 256x256, 4 LDS bufs, counted vmcnt, conflict-free
// (r>>1)&3 swizzle, XCD panel-major mapping.
// ---------------------------------------------------------------------------
__global__ __launch_bounds__(512, 2) void gemm_head8(
    const ushort* __restrict__ A, const ushort* __restrict__ B,
    float* __restrict__ C) {
  __shared__ char lds[131072];
  const int tid = threadIdx.x;
  const int l = tid & 63;
  const int wid = __builtin_amdgcn_readfirstlane(tid >> 6);
  const int wm = wid >> 2, wn = wid & 3;

  const int bid = blockIdx.x;
  const int swz = (bid & 7) * 197 + (bid >> 3);
  const int pan = swz >> 3, mrw = swz & 7;
  const int m0 = mrw * 256;
  const int n0 = pan * 256;

  const ushort* gA[2];
  const ushort* gB[2];
#pragma unroll
  for (int j = 0; j < 2; j++) {
    const int c = tid + j * 512;
    const int r = c >> 2, kq = c & 3;
    gA[j] = A + (size_t)(m0 + r) * Dm + ((kq ^ ((r >> 1) & 3)) * 8);
    int rb = n0 + r;
    rb = min(rb, Vv - 1);
    gB[j] = B + (size_t)rb * Dm + ((kq ^ ((r >> 1) & 3)) * 8);
  }

#define HSTAGE(t)                                                            \
  do {                                                                       \
    char* _lb = lds + ((t) & 3) * 32768;                                     \
    const int _o = (t) * 32;                                                 \
    GLL(gA[0] + _o, _lb + tid * 16);                                         \
    GLL(gA[1] + _o, _lb + 8192 + tid * 16);                                  \
    GLL(gB[0] + _o, _lb + 16384 + tid * 16);                                 \
    GLL(gB[1] + _o, _lb + 24576 + tid * 16);                                 \
  } while (0)

  f32x4 acc[8][4] = {};
  const int s = l & 15, g = l >> 4;

  int aOff[8], bOff[4];
#pragma unroll
  for (int fm = 0; fm < 8; fm++) {
    const int r = wm * 128 + fm * 16 + s;
    aOff[fm] = r * 64 + ((g ^ ((r >> 1) & 3)) * 16);
  }
#pragma unroll
  for (int fn = 0; fn < 4; fn++) {
    const int r = wn * 64 + fn * 16 + s;
    bOff[fn] = 16384 + r * 64 + ((g ^ ((r >> 1) & 3)) * 16);
  }

  HSTAGE(0); HSTAGE(1); HSTAGE(2);
  asm volatile("s_waitcnt vmcnt(8)" ::: "memory");
  __builtin_amdgcn_s_barrier();
  __builtin_amdgcn_sched_barrier(0);

#define HITER(t, VC)                                                         \
  {                                                                          \
    if ((t) + 3 < 24) HSTAGE((t) + 3);                                       \
    char* bb = lds + ((t) & 3) * 32768;                                      \
    bf16x8 av[8], bv[4];                                                     \
    _Pragma("unroll")                                                        \
    for (int fm = 0; fm < 8; fm++) av[fm] = *(const bf16x8*)(bb + aOff[fm]); \
    _Pragma("unroll")                                                        \
    for (int fn = 0; fn < 4; fn++) bv[fn] = *(const bf16x8*)(bb + bOff[fn]); \
    __builtin_amdgcn_s_setprio(1);                                           \
    _Pragma("unroll")                                                        \
    for (int fm = 0; fm < 8; fm++)                                           \
      _Pragma("unroll")                                                      \
      for (int fn = 0; fn < 4; fn++)                                         \
        acc[fm][fn] = __builtin_amdgcn_mfma_f32_16x16x32_bf16(               \
            av[fm], bv[fn], acc[fm][fn], 0, 0, 0);                           \
    __builtin_amdgcn_s_setprio(0);                                           \
    asm volatile("s_waitcnt lgkmcnt(0)" ::: "memory");                       \
    asm volatile("s_waitcnt vmcnt(" #VC ")" ::: "memory");                   \
    __builtin_amdgcn_s_barrier();                                            \
    __builtin_amdgcn_sched_barrier(0);                                       \
  }

#pragma unroll 1
  for (int t = 0; t <= 20; ++t) HITER(t, 8);
  HITER(21, 4);
  HITER(22, 0);
  HITER(23, 0);

#pragma unroll
  for (int fm = 0; fm < 8; ++fm) {
    const int row0 = m0 + wm * 128 + fm * 16 + g * 4;
#pragma unroll
    for (int fn = 0; fn < 4; ++fn) {
      const int col = n0 + wn * 64 + fn * 16 + s;
      if (col >= Vv) continue;
#pragma unroll
      for (int r = 0; r < 4; ++r)
        C[(size_t)(row0 + r) * Vv + col] = acc[fm][fn][r];
    }
  }
}

// ---------------------------------------------------------------------------
// MFMA flash attention (R8, unchanged).
// ---------------------------------------------------------------------------
__global__ __launch_bounds__(128) void attn_mfma(
    const ushort* __restrict__ qkv, const ushort* __restrict__ vTg,
    ushort* __restrict__ y) {
  __shared__ char lds[36864];
  const int tid = threadIdx.x;
  const int l = tid & 63;
  const int w = tid >> 6;
  const int s = l & 15, g = l >> 4;
  const int bq = gridDim.x - 1 - blockIdx.x;
  const int h = blockIdx.y, b = blockIdx.z;
  const int bh = b * Hh + h;

  const int qrow = bq * 32 + w * 16 + s;
  const ushort* qp = qkv + (size_t)(b * Tt + qrow) * 2304 + h * 64 + g * 8;
  const bf16x8 aq0 = *(const bf16x8*)qp;
  const bf16x8 aq1 = *(const bf16x8*)(qp + 32);

  size_t gofs[8];
#pragma unroll
  for (int i = 0; i < 8; i++) {
    const int c = tid + i * 128;
    if (i < 4) {
      const int kr = c >> 3;
      gofs[i] = (size_t)(b * Tt + kr) * 2304 + Dm + h * 64 + ((c & 7) ^ (kr & 7)) * 8;
    } else {
      const int cv = c - 512;
      const int vr = cv >> 3;
      gofs[i] = (size_t)(bh * 64 + vr) * Tt + ((cv & 7) ^ (vr & 7)) * 8;
    }
  }

#define ASTAGE(kt, base)                                                     \
  do {                                                                       \
    _Pragma("unroll")                                                        \
    for (int i = 0; i < 8; i++) {                                            \
      const ushort* p = (i < 4) ? (qkv + gofs[i] + (size_t)(kt) * 147456)    \
                                : (vTg + gofs[i] + (kt) * 64);               \
      GLL(p, lds + (base) + tid * 16 + i * 2048);                            \
    }                                                                        \
  } while (0)

  f32x4 oc[4] = {};
  float mrun[4], lrun[4];
#pragma unroll
  for (int r = 0; r < 4; r++) { mrun[r] = -INFINITY; lrun[r] = 0.f; }

  const int pB = 32768 + w * 2048;
  const int kSw = (s & 7);
  const int nkt = (bq >> 1) + 1;

  ASTAGE(0, 0);
  for (int kt = 0; kt < nkt; ++kt) {
    __syncthreads();
    if (kt + 1 < nkt) ASTAGE(kt + 1, ((kt + 1) & 1) * 16384);
    const int cur = (kt & 1) * 16384;

    f32x4 sc[4];
    __builtin_amdgcn_s_setprio(1);
#pragma unroll
    for (int jn = 0; jn < 4; jn++) {
      const int krow = cur + (jn * 16 + s) * 128;
      const bf16x8 bk0 = *(const bf16x8*)(lds + krow + ((g ^ kSw) * 16));
      const bf16x8 bk1 = *(const bf16x8*)(lds + krow + (((4 + g) ^ kSw) * 16));
      f32x4 z = {};
      z = __builtin_amdgcn_mfma_f32_16x16x32_bf16(aq0, bk0, z, 0, 0, 0);
      z = __builtin_amdgcn_mfma_f32_16x16x32_bf16(aq1, bk1, z, 0, 0, 0);
      sc[jn] = z;
    }
    __builtin_amdgcn_s_setprio(0);

    float cr[4];
    const bool diag = (kt == nkt - 1);
#pragma unroll
    for (int r = 0; r < 4; r++) {
      const int rowg = bq * 32 + w * 16 + g * 4 + r;
      float v[4];
#pragma unroll
      for (int jn = 0; jn < 4; jn++) {
        v[jn] = sc[jn][r] * 0.125f;
        if (diag && (kt * 64 + jn * 16 + s) > rowg) v[jn] = -INFINITY;
      }
      float mx = fmaxf(fmaxf(v[0], v[1]), fmaxf(v[2], v[3]));
      mx = fmaxf(mx, __shfl_xor(mx, 1));
      mx = fmaxf(mx, __shfl_xor(mx, 2));
      mx = fmaxf(mx, __shfl_xor(mx, 4));
      mx = fmaxf(mx, __shfl_xor(mx, 8));
      const float mnew = fmaxf(mrun[r], mx);
      const float corr = __expf(mrun[r] - mnew);
      mrun[r] = mnew;
      float ps = 0.f;
#pragma unroll
      for (int jn = 0; jn < 4; jn++) {
        const float p = __expf(v[jn] - mnew);
        ps += p;
        *(ushort*)(lds + pB + (g * 4 + r) * 128 +
                   (((2 * jn + (s >> 3)) ^ g) * 16) + (s & 7) * 2) = f2bf(p);
      }
      ps += __shfl_xor(ps, 1);
      ps += __shfl_xor(ps, 2);
      ps += __shfl_xor(ps, 4);
      ps += __shfl_xor(ps, 8);
      lrun[r] = lrun[r] * corr + ps;
      cr[r] = corr;
    }

    const float c01 = (s & 1) ? cr[1] : cr[0];
    const float c23 = (s & 1) ? cr[3] : cr[2];
    const float csel = (s & 2) ? c23 : c01;
    const float ccol = __shfl(csel, ((s >> 2) << 4) | s);
#pragma unroll
    for (int fm = 0; fm < 4; fm++) {
      oc[fm][0] *= ccol; oc[fm][1] *= ccol;
      oc[fm][2] *= ccol; oc[fm][3] *= ccol;
    }

    const bf16x8 bp0 = *(const bf16x8*)(lds + pB + s * 128 + ((g ^ (s >> 2)) * 16));
    const bf16x8 bp1 = *(const bf16x8*)(lds + pB + s * 128 + (((4 + g) ^ (s >> 2)) * 16));
    __builtin_amdgcn_s_setprio(1);
#pragma unroll
    for (int fm = 0; fm < 4; fm++) {
      const int vrow = cur + 8192 + (fm * 16 + s) * 128;
      const bf16x8 av0 = *(const bf16x8*)(lds + vrow + ((g ^ kSw) * 16));
      const bf16x8 av1 = *(const bf16x8*)(lds + vrow + (((4 + g) ^ kSw) * 16));
      oc[fm] = __builtin_amdgcn_mfma_f32_16x16x32_bf16(av0, bp0, oc[fm], 0, 0, 0);
      oc[fm] = __builtin_amdgcn_mfma_f32_16x16x32_bf16(av1, bp1, oc[fm], 0, 0, 0);
    }
    __builtin_amdgcn_s_setprio(0);
  }

  float li[4];
#pragma unroll
  for (int r = 0; r < 4; r++) li[r] = 1.f / lrun[r];
  const float l01 = (s & 1) ? li[1] : li[0];
  const float l23 = (s & 1) ? li[3] : li[2];
  const float lsel = (s & 2) ? l23 : l01;
  const float lcol = __shfl(lsel, ((s >> 2) << 4) | s);
  ushort* yp = y + (size_t)(b * Tt + qrow) * Dm + h * 64;
#pragma unroll
  for (int fm = 0; fm < 4; fm++) {
    ushort4 o4;
    o4.x = f2bf(oc[fm][0] * lcol);
    o4.y = f2bf(oc[fm][1] * lcol);
    o4.z = f2bf(oc[fm][2] * lcol);
    o4.w = f2bf(oc[fm][3] * lcol);
    *(ushort4*)(yp + fm * 16 + g * 4) = o4;
  }
}

// ---------------------------------------------------------------------------
extern "C" void kernel_launch(void* const* d_in, const int* in_sizes, int n_in,
                              void* d_out, int out_size, void* d_ws, size_t ws_size,
                              hipStream_t stream) {
  const int* idx = (const int*)d_in[0];
  const float* tok = (const float*)d_in[1];
  const float* pos = (const float*)d_in[2];
  const float* ln1w = (const float*)d_in[3];
  const float* ln1b = (const float*)d_in[4];
  const float* qkvw = (const float*)d_in[5];
  const float* qkvb = (const float*)d_in[6];
  const float* projw = (const float*)d_in[7];
  const float* projb = (const float*)d_in[8];
  const float* ln2w = (const float*)d_in[9];
  const float* ln2b = (const float*)d_in[10];
  const float* ff1w = (const float*)d_in[11];
  const float* ff1b = (const float*)d_in[12];
  const float* ff2w = (const float*)d_in[13];
  const float* ff2b = (const float*)d_in[14];
  const float* lnfw = (const float*)d_in[15];
  const float* lnfb = (const float*)d_in[16];
  const float* headw = (const float*)d_in[17];
  float* out = (float*)d_out;

  char* ws = (char*)d_ws;
  ushort* h    = (ushort*)ws;                    // [2048][768] bf16
  float*  x    = (float*)(ws + 3145728);         // [2048][768] fp32
  ushort* y    = (ushort*)(ws + 9437184);        // [2048][768] bf16
  ushort* qkv  = (ushort*)(ws + 12582912);       // [2048][2304] bf16
  ushort* vTg  = (ushort*)(ws + 22020096);       // [24][64][1024] bf16
  ushort* ff   = (ushort*)(ws + 25165824);       // [2048][4096] bf16
  ushort* wb   = (ushort*)(ws + 41943040);       // all weights bf16 (285MB)
  // dedicated split-K partial buffers (free region past loop weights is NOT
  // free — wb holds all weights again; use the tail past wb+285MB? ws proven
  // >= 327MB only. Overlay like R8 instead: 4 slices need 25MB each.
  // proj partials: over qkv+vTg+ff head space: ws+12582912 .. +25MB (qkv 9.4
  // + vTg 3.1 + ff first 12.7MB? ff needed only AFTER red_ln consumes proj
  // partials -> safe. ff2 partials: over y+qkv+vTg (15.7MB) + ff tail? ff is
  // INPUT of ff2 gemm — cannot overlay. Use y+qkv+vTg = 15.7MB < 25MB.
  // -> keep proj split-4 (over qkv/vTg/ff-head), ff2 stays split-2.
  float* projPart = (float*)(ws + 12582912);     // 4x6.29MB over qkv+vT+ff[0:12.6MB]
  float* ff2Part  = (float*)(ws + 9437184);      // 2x6.29MB over y+qkv

  const size_t oPROJ = (size_t)Ll * 3 * Dm * Dm;           // 21233664
  const size_t oFF1  = oPROJ + (size_t)Ll * Dm * Dm;       // 28311552
  const size_t oFF2  = oFF1 + (size_t)Ll * DFF * Dm;       // 66060288
  const size_t oHEAD = oFF2 + (size_t)Ll * Dm * DFF;       // 103809024

  convert_w<<<2048, 256, 0, stream>>>(qkvw, wb, (int)(oPROJ / 4));
  convert_w<<<2048, 256, 0, stream>>>(projw, wb + oPROJ, (int)((oFF1 - oPROJ) / 4));
  convert_w<<<2048, 256, 0, stream>>>(ff1w, wb + oFF1, (int)((oFF2 - oFF1) / 4));
  convert_w<<<2048, 256, 0, stream>>>(ff2w, wb + oFF2, (int)((oHEAD - oFF2) / 4));
  convert_w<<<2048, 256, 0, stream>>>(headw, wb + oHEAD, (int)((size_t)Vv * Dm / 4));

  embed_ln<<<ROWS, 256, 0, stream>>>(idx, tok, pos, ln1w, ln1b, x, h);

  for (int l = 0; l < Ll; l++) {
    gemm_mfma<EPI_QKV><<<dim3(18, 16), 256, 0, stream>>>(
        h, wb + (size_t)l * 3 * Dm * Dm, qkvb + l * 3 * Dm, qkv, vTg,
        Dm, Dm, 3 * Dm, 3 * Dm);
    attn_mfma<<<dim3(32, Hh, Bb), 128, 0, stream>>>(qkv, vTg, y);
    gemm_mfma<EPI_PART><<<dim3(6, 16, 4), 256, 0, stream>>>(
        y, wb + oPROJ + (size_t)l * Dm * Dm, nullptr, projPart, nullptr,
        Dm / 4, Dm, Dm, Dm);
    red_ln<<<ROWS, 192, 0, stream>>>(projPart, 4, projb + l * Dm, x,
                                     ln2w + l * Dm, ln2b + l * Dm, h);
    gemm_mfma<EPI_BIAS_GELU><<<dim3(32, 16), 256, 0, stream>>>(
        h, wb + oFF1 + (size_t)l * DFF * Dm, ff1b + l * DFF, ff, nullptr,
        Dm, Dm, DFF, DFF);
    gemm_mfma<EPI_PART><<<dim3(6, 16, 2), 256, 0, stream>>>(
        ff, wb + oFF2 + (size_t)l * Dm * DFF, nullptr, ff2Part, nullptr,
        DFF / 2, DFF, Dm, Dm);
    const float* nw = (l == Ll - 1) ? lnfw : ln1w + (l + 1) * Dm;
    const float* nb = (l == Ll - 1) ? lnfb : ln1b + (l + 1) * Dm;
    red_ln<<<ROWS, 192, 0, stream>>>(ff2Part, 2, ff2b + l * Dm, x, nw, nb, h);
  }

  gemm_head8<<<1576, 512, 0, stream>>>(h, wb + oHEAD, out);
}

// Round 11
// 2069.456 us; speedup vs baseline: 1.2361x; 1.0605x over previous
//
#include <hip/hip_runtime.h>
#include <hip/hip_bf16.h>
#include <math.h>

#define Dm 768
#define Tt 1024
#define Bb 2
#define Hh 12
#define DFF 4096
#define Ll 12
#define Vv 50257
#define ROWS (Bb*Tt)   // 2048
#define LN_EPS 1e-5f

typedef unsigned int uint;
typedef unsigned short ushort;
typedef float f32x4 __attribute__((ext_vector_type(4)));
typedef short bf16x8 __attribute__((ext_vector_type(8)));
typedef ushort us8 __attribute__((ext_vector_type(8)));

__device__ __forceinline__ ushort f2bf(float f) {
  uint u = __builtin_bit_cast(uint, f);
  u += 0x7FFFu + ((u >> 16) & 1u);   // RNE
  return (ushort)(u >> 16);
}

#define GLL(gp, lp)                                                          \
  __builtin_amdgcn_global_load_lds(                                          \
      (const __attribute__((address_space(1))) uint*)(gp),                   \
      (__attribute__((address_space(3))) uint*)(lp), 16, 0, 0)

// ---------------------------------------------------------------------------
// Fused embedding + LayerNorm: x = tok[idx]+pos (fp32), h = LN(x) (bf16)
// ---------------------------------------------------------------------------
__global__ __launch_bounds__(256) void embed_ln(
    const int* __restrict__ idx, const float* __restrict__ tok,
    const float* __restrict__ pos, const float* __restrict__ w,
    const float* __restrict__ b, float* __restrict__ x,
    ushort* __restrict__ out) {
  const int row = blockIdx.x;
  const int t = row & (Tt - 1);
  const int tid = threadIdx.x;
  const float* tsrc = tok + (size_t)idx[row] * Dm;
  const float* psrc = pos + (size_t)t * Dm;
  float v[3];
  float sum = 0.f, sq = 0.f;
#pragma unroll
  for (int i = 0; i < 3; i++) {
    const int d = tid + i * 256;
    v[i] = tsrc[d] + psrc[d];
    x[(size_t)row * Dm + d] = v[i];
    sum += v[i]; sq += v[i] * v[i];
  }
#pragma unroll
  for (int off = 32; off > 0; off >>= 1) {
    sum += __shfl_xor(sum, off);
    sq  += __shfl_xor(sq, off);
  }
  __shared__ float red[8];
  const int wid = tid >> 6, lane = tid & 63;
  if (lane == 0) { red[wid] = sum; red[wid + 4] = sq; }
  __syncthreads();
  sum = red[0] + red[1] + red[2] + red[3];
  sq  = red[4] + red[5] + red[6] + red[7];
  const float mu = sum * (1.f / Dm);
  const float var = sq * (1.f / Dm) - mu * mu;
  const float rstd = rsqrtf(var + LN_EPS);
  ushort* dst = out + (size_t)row * Dm;
#pragma unroll
  for (int i = 0; i < 3; i++) {
    const int d = tid + i * 256;
    dst[d] = f2bf((v[i] - mu) * rstd * w[d] + b[d]);
  }
}

// ---------------------------------------------------------------------------
// Fused split-K reduce + bias + residual + LayerNorm -> bf16 h
// 192 threads, float4 per thread (768 = 192*4).
// ---------------------------------------------------------------------------
__global__ __launch_bounds__(192) void red_ln(
    const float* __restrict__ part, int nsk, const float* __restrict__ bias,
    float* __restrict__ x, const float* __restrict__ w,
    const float* __restrict__ b, ushort* __restrict__ out) {
  const int row = blockIdx.x;
  const int tid = threadIdx.x;
  const size_t o4 = (size_t)row * 192 + tid;
  float4 xv = ((const float4*)x)[o4];
  const float4 b4 = ((const float4*)bias)[tid];
  xv.x += b4.x; xv.y += b4.y; xv.z += b4.z; xv.w += b4.w;
  for (int k = 0; k < nsk; k++) {
    const float4 p = ((const float4*)part)[(size_t)k * ROWS * 192 + o4];
    xv.x += p.x; xv.y += p.y; xv.z += p.z; xv.w += p.w;
  }
  ((float4*)x)[o4] = xv;
  float sum = xv.x + xv.y + xv.z + xv.w;
  float sq = xv.x * xv.x + xv.y * xv.y + xv.z * xv.z + xv.w * xv.w;
#pragma unroll
  for (int off = 32; off > 0; off >>= 1) {
    sum += __shfl_xor(sum, off);
    sq  += __shfl_xor(sq, off);
  }
  __shared__ float red[6];
  const int wid = tid >> 6, lane = tid & 63;
  if (lane == 0) { red[wid] = sum; red[wid + 3] = sq; }
  __syncthreads();
  sum = red[0] + red[1] + red[2];
  sq  = red[3] + red[4] + red[5];
  const float mu = sum * (1.f / Dm);
  const float var = sq * (1.f / Dm) - mu * mu;
  const float rstd = rsqrtf(var + LN_EPS);
  const float4 w4 = ((const float4*)w)[tid];
  const float4 bb4 = ((const float4*)b)[tid];
  ushort4 o;
  o.x = f2bf((xv.x - mu) * rstd * w4.x + bb4.x);
  o.y = f2bf((xv.y - mu) * rstd * w4.y + bb4.y);
  o.z = f2bf((xv.z - mu) * rstd * w4.z + bb4.z);
  o.w = f2bf((xv.w - mu) * rstd * w4.w + bb4.w);
  ((ushort4*)out)[o4] = o;
}

// ---------------------------------------------------------------------------
// Weight converter fp32 -> bf16 (count in float4 units, contiguous)
// ---------------------------------------------------------------------------
__global__ __launch_bounds__(256) void convert_w(
    const float* __restrict__ s, ushort* __restrict__ d, int n4) {
  const int stride = gridDim.x * 256;
  for (int i = blockIdx.x * 256 + threadIdx.x; i < n4; i += stride) {
    const float4 v = ((const float4*)s)[i];
    ushort4 o;
    o.x = f2bf(v.x); o.y = f2bf(v.y); o.z = f2bf(v.z); o.w = f2bf(v.w);
    ((ushort4*)d)[i] = o;
  }
}

// ---------------------------------------------------------------------------
// bf16 MFMA GEMM (loop GEMMs): C[M,Nloc] = A[M,*]@B[N,*]^T + epi.
// EPI_PART: blockIdx.z = split-k index (nsk from gridDim.z).
// ---------------------------------------------------------------------------
#define EPI_QKV 0
#define EPI_PART 1
#define EPI_BIAS_GELU 2
#define EPI_NONE 3

template <int EPI>
__global__ __launch_bounds__(256) void gemm_mfma(
    const ushort* __restrict__ A, const ushort* __restrict__ B,
    const float* __restrict__ bias, void* __restrict__ Cv,
    void* __restrict__ Cv2, int Kloop, int Kstr, int Nloc, int ldC) {
  __shared__ char lds[32768];           // 2 x (A 8KB + B 8KB)
  const int tid = threadIdx.x;
  const int l = tid & 63;
  const int wid = __builtin_amdgcn_readfirstlane(tid >> 6);
  const int wr = wid >> 1, wc = wid & 1;
  const int m0 = blockIdx.y * 128;
  const int n0 = blockIdx.x * 128;
  const int z = (EPI == EPI_PART) ? blockIdx.z : 0;
  if (EPI == EPI_PART) { A += (size_t)z * Kloop; B += (size_t)z * Kloop; }

  const int cperm = (((l & 3) ^ ((l >> 3) & 3)) * 8);
  const ushort* gA = A + (size_t)(m0 + wid * 32 + (l >> 2)) * Kstr + cperm;
  int rB = n0 + wid * 32 + (l >> 2);
  rB = min(rB, Nloc - 1);
  const ushort* gB = B + (size_t)rB * Kstr + cperm;

  const int rdSw = (l & 15) * 64 + (((l >> 4) ^ ((l >> 1) & 3)) * 16);
  const int aRd = wr * 4096 + rdSw;
  const int bRd = 8192 + wc * 4096 + rdSw;

  f32x4 acc[4][4] = {};
  const int nt = Kloop / 32;

  {
    const int lb = wid * 2048;
    GLL(gA, lds + lb);          GLL(gA + 16 * Kstr, lds + lb + 1024);
    GLL(gB, lds + 8192 + lb);   GLL(gB + 16 * Kstr, lds + 8192 + lb + 1024);
  }

  for (int t = 0; t < nt; ++t) {
    __syncthreads();
    if (t + 1 < nt) {
      const int base = ((t + 1) & 1) * 16384;
      const int lb = base + wid * 2048;
      const ushort* a = gA + (t + 1) * 32;
      const ushort* b = gB + (t + 1) * 32;
      GLL(a, lds + lb);         GLL(a + 16 * Kstr, lds + lb + 1024);
      GLL(b, lds + 8192 + lb);  GLL(b + 16 * Kstr, lds + 8192 + lb + 1024);
    }
    const int base = (t & 1) * 16384;
    bf16x8 av[4], bv[4];
#pragma unroll
    for (int i = 0; i < 4; ++i) {
      av[i] = *(const bf16x8*)(lds + base + aRd + i * 1024);
      bv[i] = *(const bf16x8*)(lds + base + bRd + i * 1024);
    }
#pragma unroll
    for (int i = 0; i < 4; ++i)
#pragma unroll
      for (int j = 0; j < 4; ++j)
        acc[i][j] = __builtin_amdgcn_mfma_f32_16x16x32_bf16(
            av[i], bv[j], acc[i][j], 0, 0, 0);
  }

#pragma unroll
  for (int fm = 0; fm < 4; ++fm) {
    const int row0 = m0 + wr * 64 + fm * 16 + (l >> 4) * 4;
#pragma unroll
    for (int fn = 0; fn < 4; ++fn) {
      const int col = n0 + wc * 64 + fn * 16 + (l & 15);
      if (col >= Nloc) continue;
      float bi = 0.f;
      if (EPI == EPI_QKV || EPI == EPI_BIAS_GELU) bi = bias[col];
      if (EPI == EPI_QKV && col >= 2 * Dm) {
        const int hh = (col - 2 * Dm) >> 6, dd = col & 63;
        const int bI = row0 >> 10, t0 = row0 & (Tt - 1);
        ushort4 o4;
        o4.x = f2bf(acc[fm][fn][0] + bi);
        o4.y = f2bf(acc[fm][fn][1] + bi);
        o4.z = f2bf(acc[fm][fn][2] + bi);
        o4.w = f2bf(acc[fm][fn][3] + bi);
        *(ushort4*)((ushort*)Cv2 +
                    ((size_t)((bI * Hh + hh) * 64 + dd)) * Tt + t0) = o4;
        continue;
      }
#pragma unroll
      for (int r = 0; r < 4; ++r) {
        float v = acc[fm][fn][r] + bi;
        const size_t off = (size_t)(row0 + r) * ldC + col;
        if (EPI == EPI_BIAS_GELU) {
          v = 0.5f * v * (1.f + erff(v * 0.70710678118654752f));
          ((ushort*)Cv)[off] = f2bf(v);
        } else if (EPI == EPI_QKV) {
          ((ushort*)Cv)[off] = f2bf(v);
        } else if (EPI == EPI_PART) {
          ((float*)Cv)[(size_t)z * ROWS * ldC + off] = v;
        } else {
          ((float*)Cv)[off] = v;
        }
      }
    }
  }
}

// ---------------------------------------------------------------------------
// Head GEMM (R8): 256x256, 4 LDS bufs, counted vmcnt, conflict-free
// (r>>1)&3 swizzle, XCD panel-major mapping.
// ---------------------------------------------------------------------------
__global__ __launch_bounds__(512, 2) void gemm_head8(
    const ushort* __restrict__ A, const ushort* __restrict__ B,
    float* __restrict__ C) {
  __shared__ char lds[131072];
  const int tid = threadIdx.x;
  const int l = tid & 63;
  const int wid = __builtin_amdgcn_readfirstlane(tid >> 6);
  const int wm = wid >> 2, wn = wid & 3;

  const int bid = blockIdx.x;
  const int swz = (bid & 7) * 197 + (bid >> 3);
  const int pan = swz >> 3, mrw = swz & 7;
  const int m0 = mrw * 256;
  const int n0 = pan * 256;

  const ushort* gA[2];
  const ushort* gB[2];
#pragma unroll
  for (int j = 0; j < 2; j++) {
    const int c = tid + j * 512;
    const int r = c >> 2, kq = c & 3;
    gA[j] = A + (size_t)(m0 + r) * Dm + ((kq ^ ((r >> 1) & 3)) * 8);
    int rb = n0 + r;
    rb = min(rb, Vv - 1);
    gB[j] = B + (size_t)rb * Dm + ((kq ^ ((r >> 1) & 3)) * 8);
  }

#define HSTAGE(t)                                                            \
  do {                                                                       \
    char* _lb = lds + ((t) & 3) * 32768;                                     \
    const int _o = (t) * 32;                                                 \
    GLL(gA[0] + _o, _lb + tid * 16);                                         \
    GLL(gA[1] + _o, _lb + 8192 + tid * 16);                                  \
    GLL(gB[0] + _o, _lb + 16384 + tid * 16);                                 \
    GLL(gB[1] + _o, _lb + 24576 + tid * 16);                                 \
  } while (0)

  f32x4 acc[8][4] = {};
  const int s = l & 15, g = l >> 4;

  int aOff[8], bOff[4];
#pragma unroll
  for (int fm = 0; fm < 8; fm++) {
    const int r = wm * 128 + fm * 16 + s;
    aOff[fm] = r * 64 + ((g ^ ((r >> 1) & 3)) * 16);
  }
#pragma unroll
  for (int fn = 0; fn < 4; fn++) {
    const int r = wn * 64 + fn * 16 + s;
    bOff[fn] = 16384 + r * 64 + ((g ^ ((r >> 1) & 3)) * 16);
  }

  HSTAGE(0); HSTAGE(1); HSTAGE(2);
  asm volatile("s_waitcnt vmcnt(8)" ::: "memory");
  __builtin_amdgcn_s_barrier();
  __builtin_amdgcn_sched_barrier(0);

#define HITER(t, VC)                                                         \
  {                                                                          \
    if ((t) + 3 < 24) HSTAGE((t) + 3);                                       \
    char* bb = lds + ((t) & 3) * 32768;                                      \
    bf16x8 av[8], bv[4];                                                     \
    _Pragma("unroll")                                                        \
    for (int fm = 0; fm < 8; fm++) av[fm] = *(const bf16x8*)(bb + aOff[fm]); \
    _Pragma("unroll")                                                        \
    for (int fn = 0; fn < 4; fn++) bv[fn] = *(const bf16x8*)(bb + bOff[fn]); \
    __builtin_amdgcn_s_setprio(1);                                           \
    _Pragma("unroll")                                                        \
    for (int fm = 0; fm < 8; fm++)                                           \
      _Pragma("unroll")                                                      \
      for (int fn = 0; fn < 4; fn++)                                         \
        acc[fm][fn] = __builtin_amdgcn_mfma_f32_16x16x32_bf16(               \
            av[fm], bv[fn], acc[fm][fn], 0, 0, 0);                           \
    __builtin_amdgcn_s_setprio(0);                                           \
    asm volatile("s_waitcnt lgkmcnt(0)" ::: "memory");                       \
    asm volatile("s_waitcnt vmcnt(" #VC ")" ::: "memory");                   \
    __builtin_amdgcn_s_barrier();                                            \
    __builtin_amdgcn_sched_barrier(0);                                       \
  }

#pragma unroll 1
  for (int t = 0; t <= 20; ++t) HITER(t, 8);
  HITER(21, 4);
  HITER(22, 0);
  HITER(23, 0);

#pragma unroll
  for (int fm = 0; fm < 8; ++fm) {
    const int row0 = m0 + wm * 128 + fm * 16 + g * 4;
#pragma unroll
    for (int fn = 0; fn < 4; ++fn) {
      const int col = n0 + wn * 64 + fn * 16 + s;
      if (col >= Vv) continue;
#pragma unroll
      for (int r = 0; r < 4; ++r)
        C[(size_t)(row0 + r) * Vv + col] = acc[fm][fn][r];
    }
  }
}

// ---------------------------------------------------------------------------
// MFMA flash attention (R8, unchanged).
// ---------------------------------------------------------------------------
__global__ __launch_bounds__(128) void attn_mfma(
    const ushort* __restrict__ qkv, const ushort* __restrict__ vTg,
    ushort* __restrict__ y) {
  __shared__ char lds[36864];
  const int tid = threadIdx.x;
  const int l = tid & 63;
  const int w = tid >> 6;
  const int s = l & 15, g = l >> 4;
  const int bq = gridDim.x - 1 - blockIdx.x;
  const int h = blockIdx.y, b = blockIdx.z;
  const int bh = b * Hh + h;

  const int qrow = bq * 32 + w * 16 + s;
  const ushort* qp = qkv + (size_t)(b * Tt + qrow) * 2304 + h * 64 + g * 8;
  const bf16x8 aq0 = *(const bf16x8*)qp;
  const bf16x8 aq1 = *(const bf16x8*)(qp + 32);

  size_t gofs[8];
#pragma unroll
  for (int i = 0; i < 8; i++) {
    const int c = tid + i * 128;
    if (i < 4) {
      const int kr = c >> 3;
      gofs[i] = (size_t)(b * Tt + kr) * 2304 + Dm + h * 64 + ((c & 7) ^ (kr & 7)) * 8;
    } else {
      const int cv = c - 512;
      const int vr = cv >> 3;
      gofs[i] = (size_t)(bh * 64 + vr) * Tt + ((cv & 7) ^ (vr & 7)) * 8;
    }
  }

#define ASTAGE(kt, base)                                                     \
  do {                                                                       \
    _Pragma("unroll")                                                        \
    for (int i = 0; i < 8; i++) {                                            \
      const ushort* p = (i < 4) ? (qkv + gofs[i] + (size_t)(kt) * 147456)    \
                                : (vTg + gofs[i] + (kt) * 64);               \
      GLL(p, lds + (base) + tid * 16 + i * 2048);                            \
    }                                                                        \
  } while (0)

  f32x4 oc[4] = {};
  float mrun[4], lrun[4];
#pragma unroll
  for (int r = 0; r < 4; r++) { mrun[r] = -INFINITY; lrun[r] = 0.f; }

  const int pB = 32768 + w * 2048;
  const int kSw = (s & 7);
  const int nkt = (bq >> 1) + 1;

  ASTAGE(0, 0);
  for (int kt = 0; kt < nkt; ++kt) {
    __syncthreads();
    if (kt + 1 < nkt) ASTAGE(kt + 1, ((kt + 1) & 1) * 16384);
    const int cur = (kt & 1) * 16384;

    f32x4 sc[4];
    __builtin_amdgcn_s_setprio(1);
#pragma unroll
    for (int jn = 0; jn < 4; jn++) {
      const int krow = cur + (jn * 16 + s) * 128;
      const bf16x8 bk0 = *(const bf16x8*)(lds + krow + ((g ^ kSw) * 16));
      const bf16x8 bk1 = *(const bf16x8*)(lds + krow + (((4 + g) ^ kSw) * 16));
      f32x4 z = {};
      z = __builtin_amdgcn_mfma_f32_16x16x32_bf16(aq0, bk0, z, 0, 0, 0);
      z = __builtin_amdgcn_mfma_f32_16x16x32_bf16(aq1, bk1, z, 0, 0, 0);
      sc[jn] = z;
    }
    __builtin_amdgcn_s_setprio(0);

    float cr[4];
    const bool diag = (kt == nkt - 1);
#pragma unroll
    for (int r = 0; r < 4; r++) {
      const int rowg = bq * 32 + w * 16 + g * 4 + r;
      float v[4];
#pragma unroll
      for (int jn = 0; jn < 4; jn++) {
        v[jn] = sc[jn][r] * 0.125f;
        if (diag && (kt * 64 + jn * 16 + s) > rowg) v[jn] = -INFINITY;
      }
      float mx = fmaxf(fmaxf(v[0], v[1]), fmaxf(v[2], v[3]));
      mx = fmaxf(mx, __shfl_xor(mx, 1));
      mx = fmaxf(mx, __shfl_xor(mx, 2));
      mx = fmaxf(mx, __shfl_xor(mx, 4));
      mx = fmaxf(mx, __shfl_xor(mx, 8));
      const float mnew = fmaxf(mrun[r], mx);
      const float corr = __expf(mrun[r] - mnew);
      mrun[r] = mnew;
      float ps = 0.f;
#pragma unroll
      for (int jn = 0; jn < 4; jn++) {
        const float p = __expf(v[jn] - mnew);
        ps += p;
        *(ushort*)(lds + pB + (g * 4 + r) * 128 +
                   (((2 * jn + (s >> 3)) ^ g) * 16) + (s & 7) * 2) = f2bf(p);
      }
      ps += __shfl_xor(ps, 1);
      ps += __shfl_xor(ps, 2);
      ps += __shfl_xor(ps, 4);
      ps += __shfl_xor(ps, 8);
      lrun[r] = lrun[r] * corr + ps;
      cr[r] = corr;
    }

    const float c01 = (s & 1) ? cr[1] : cr[0];
    const float c23 = (s & 1) ? cr[3] : cr[2];
    const float csel = (s & 2) ? c23 : c01;
    const float ccol = __shfl(csel, ((s >> 2) << 4) | s);
#pragma unroll
    for (int fm = 0; fm < 4; fm++) {
      oc[fm][0] *= ccol; oc[fm][1] *= ccol;
      oc[fm][2] *= ccol; oc[fm][3] *= ccol;
    }

    const bf16x8 bp0 = *(const bf16x8*)(lds + pB + s * 128 + ((g ^ (s >> 2)) * 16));
    const bf16x8 bp1 = *(const bf16x8*)(lds + pB + s * 128 + (((4 + g) ^ (s >> 2)) * 16));
    __builtin_amdgcn_s_setprio(1);
#pragma unroll
    for (int fm = 0; fm < 4; fm++) {
      const int vrow = cur + 8192 + (fm * 16 + s) * 128;
      const bf16x8 av0 = *(const bf16x8*)(lds + vrow + ((g ^ kSw) * 16));
      const bf16x8 av1 = *(const bf16x8*)(lds + vrow + (((4 + g) ^ kSw) * 16));
      oc[fm] = __builtin_amdgcn_mfma_f32_16x16x32_bf16(av0, bp0, oc[fm], 0, 0, 0);
      oc[fm] = __builtin_amdgcn_mfma_f32_16x16x32_bf16(av1, bp1, oc[fm], 0, 0, 0);
    }
    __builtin_amdgcn_s_setprio(0);
  }

  float li[4];
#pragma unroll
  for (int r = 0; r < 4; r++) li[r] = 1.f / lrun[r];
  const float l01 = (s & 1) ? li[1] : li[0];
  const float l23 = (s & 1) ? li[3] : li[2];
  const float lsel = (s & 2) ? l23 : l01;
  const float lcol = __shfl(lsel, ((s >> 2) << 4) | s);
  ushort* yp = y + (size_t)(b * Tt + qrow) * Dm + h * 64;
#pragma unroll
  for (int fm = 0; fm < 4; fm++) {
    ushort4 o4;
    o4.x = f2bf(oc[fm][0] * lcol);
    o4.y = f2bf(oc[fm][1] * lcol);
    o4.z = f2bf(oc[fm][2] * lcol);
    o4.w = f2bf(oc[fm][3] * lcol);
    *(ushort4*)(yp + fm * 16 + g * 4) = o4;
  }
}

// ---------------------------------------------------------------------------
extern "C" void kernel_launch(void* const* d_in, const int* in_sizes, int n_in,
                              void* d_out, int out_size, void* d_ws, size_t ws_size,
                              hipStream_t stream) {
  const int* idx = (const int*)d_in[0];
  const float* tok = (const float*)d_in[1];
  const float* pos = (const float*)d_in[2];
  const float* ln1w = (const float*)d_in[3];
  const float* ln1b = (const float*)d_in[4];
  const float* qkvw = (const float*)d_in[5];
  const float* qkvb = (const float*)d_in[6];
  const float* projw = (const float*)d_in[7];
  const float* projb = (const float*)d_in[8];
  const float* ln2w = (const float*)d_in[9];
  const float* ln2b = (const float*)d_in[10];
  const float* ff1w = (const float*)d_in[11];
  const float* ff1b = (const float*)d_in[12];
  const float* ff2w = (const float*)d_in[13];
  const float* ff2b = (const float*)d_in[14];
  const float* lnfw = (const float*)d_in[15];
  const float* lnfb = (const float*)d_in[16];
  const float* headw = (const float*)d_in[17];
  float* out = (float*)d_out;

  char* ws = (char*)d_ws;
  ushort* h    = (ushort*)ws;                    // [2048][768] bf16
  float*  x    = (float*)(ws + 3145728);         // [2048][768] fp32
  ushort* y    = (ushort*)(ws + 9437184);        // [2048][768] bf16
  ushort* qkv  = (ushort*)(ws + 12582912);       // [2048][2304] bf16
  ushort* vTg  = (ushort*)(ws + 22020096);       // [24][64][1024] bf16
  ushort* ff   = (ushort*)(ws + 25165824);       // [2048][4096] bf16
  ushort* wb   = (ushort*)(ws + 41943040);       // all weights bf16 (284.8MB)
  // dedicated split-K partial buffers past the weights (ws ~1.6GB per
  // poison-fill WRITE_SIZE): wb ends at 41943040 + 284812800 = 326755840.
  float* projPart = (float*)(ws + 326755840);    // 4 x 6.29MB
  float* ff2Part  = (float*)(ws + 351921664);    // 4 x 6.29MB

  const size_t oPROJ = (size_t)Ll * 3 * Dm * Dm;           // 21233664
  const size_t oFF1  = oPROJ + (size_t)Ll * Dm * Dm;       // 28311552
  const size_t oFF2  = oFF1 + (size_t)Ll * DFF * Dm;       // 66060288
  const size_t oHEAD = oFF2 + (size_t)Ll * Dm * DFF;       // 103809024

  convert_w<<<2048, 256, 0, stream>>>(qkvw, wb, (int)(oPROJ / 4));
  convert_w<<<2048, 256, 0, stream>>>(projw, wb + oPROJ, (int)((oFF1 - oPROJ) / 4));
  convert_w<<<2048, 256, 0, stream>>>(ff1w, wb + oFF1, (int)((oFF2 - oFF1) / 4));
  convert_w<<<2048, 256, 0, stream>>>(ff2w, wb + oFF2, (int)((oHEAD - oFF2) / 4));
  convert_w<<<2048, 256, 0, stream>>>(headw, wb + oHEAD, (int)((size_t)Vv * Dm / 4));

  embed_ln<<<ROWS, 256, 0, stream>>>(idx, tok, pos, ln1w, ln1b, x, h);

  for (int l = 0; l < Ll; l++) {
    gemm_mfma<EPI_QKV><<<dim3(18, 16), 256, 0, stream>>>(
        h, wb + (size_t)l * 3 * Dm * Dm, qkvb + l * 3 * Dm, qkv, vTg,
        Dm, Dm, 3 * Dm, 3 * Dm);
    attn_mfma<<<dim3(32, Hh, Bb), 128, 0, stream>>>(qkv, vTg, y);
    gemm_mfma<EPI_PART><<<dim3(6, 16, 4), 256, 0, stream>>>(
        y, wb + oPROJ + (size_t)l * Dm * Dm, nullptr, projPart, nullptr,
        Dm / 4, Dm, Dm, Dm);
    red_ln<<<ROWS, 192, 0, stream>>>(projPart, 4, projb + l * Dm, x,
                                     ln2w + l * Dm, ln2b + l * Dm, h);
    gemm_mfma<EPI_BIAS_GELU><<<dim3(32, 16), 256, 0, stream>>>(
        h, wb + oFF1 + (size_t)l * DFF * Dm, ff1b + l * DFF, ff, nullptr,
        Dm, Dm, DFF, DFF);
    gemm_mfma<EPI_PART><<<dim3(6, 16, 4), 256, 0, stream>>>(
        ff, wb + oFF2 + (size_t)l * Dm * DFF, nullptr, ff2Part, nullptr,
        DFF / 4, DFF, Dm, Dm);
    const float* nw = (l == Ll - 1) ? lnfw : ln1w + (l + 1) * Dm;
    const float* nb = (l == Ll - 1) ? lnfb : ln1b + (l + 1) * Dm;
    red_ln<<<ROWS, 192, 0, stream>>>(ff2Part, 4, ff2b + l * Dm, x, nw, nb, h);
  }

  gemm_head8<<<1576, 512, 0, stream>>>(h, wb + oHEAD, out);
}

// Round 12
// 2054.808 us; speedup vs baseline: 1.2449x; 1.0071x over previous
//
#include <hip/hip_runtime.h>
#include <hip/hip_bf16.h>
#include <math.h>

#define Dm 768
#define Tt 1024
#define Bb 2
#define Hh 12
#define DFF 4096
#define Ll 12
#define Vv 50257
#define ROWS (Bb*Tt)   // 2048
#define LN_EPS 1e-5f

typedef unsigned int uint;
typedef unsigned short ushort;
typedef float f32x4 __attribute__((ext_vector_type(4)));
typedef short bf16x8 __attribute__((ext_vector_type(8)));
typedef ushort us8 __attribute__((ext_vector_type(8)));

__device__ __forceinline__ ushort f2bf(float f) {
  uint u = __builtin_bit_cast(uint, f);
  u += 0x7FFFu + ((u >> 16) & 1u);   // RNE
  return (ushort)(u >> 16);
}

#define GLL(gp, lp)                                                          \
  __builtin_amdgcn_global_load_lds(                                          \
      (const __attribute__((address_space(1))) uint*)(gp),                   \
      (__attribute__((address_space(3))) uint*)(lp), 16, 0, 0)

#define MF(a, b, c) __builtin_amdgcn_mfma_f32_16x16x32_bf16(a, b, c, 0, 0, 0)

// ---------------------------------------------------------------------------
// Fused embedding + LayerNorm
// ---------------------------------------------------------------------------
__global__ __launch_bounds__(256) void embed_ln(
    const int* __restrict__ idx, const float* __restrict__ tok,
    const float* __restrict__ pos, const float* __restrict__ w,
    const float* __restrict__ b, float* __restrict__ x,
    ushort* __restrict__ out) {
  const int row = blockIdx.x;
  const int t = row & (Tt - 1);
  const int tid = threadIdx.x;
  const float* tsrc = tok + (size_t)idx[row] * Dm;
  const float* psrc = pos + (size_t)t * Dm;
  float v[3];
  float sum = 0.f, sq = 0.f;
#pragma unroll
  for (int i = 0; i < 3; i++) {
    const int d = tid + i * 256;
    v[i] = tsrc[d] + psrc[d];
    x[(size_t)row * Dm + d] = v[i];
    sum += v[i]; sq += v[i] * v[i];
  }
#pragma unroll
  for (int off = 32; off > 0; off >>= 1) {
    sum += __shfl_xor(sum, off);
    sq  += __shfl_xor(sq, off);
  }
  __shared__ float red[8];
  const int wid = tid >> 6, lane = tid & 63;
  if (lane == 0) { red[wid] = sum; red[wid + 4] = sq; }
  __syncthreads();
  sum = red[0] + red[1] + red[2] + red[3];
  sq  = red[4] + red[5] + red[6] + red[7];
  const float mu = sum * (1.f / Dm);
  const float var = sq * (1.f / Dm) - mu * mu;
  const float rstd = rsqrtf(var + LN_EPS);
  ushort* dst = out + (size_t)row * Dm;
#pragma unroll
  for (int i = 0; i < 3; i++) {
    const int d = tid + i * 256;
    dst[d] = f2bf((v[i] - mu) * rstd * w[d] + b[d]);
  }
}

// ---------------------------------------------------------------------------
// Fused split-K reduce + bias + residual + LayerNorm -> bf16 h (192 thr)
// ---------------------------------------------------------------------------
__global__ __launch_bounds__(192) void red_ln(
    const float* __restrict__ part, int nsk, const float* __restrict__ bias,
    float* __restrict__ x, const float* __restrict__ w,
    const float* __restrict__ b, ushort* __restrict__ out) {
  const int row = blockIdx.x;
  const int tid = threadIdx.x;
  const size_t o4 = (size_t)row * 192 + tid;
  float4 xv = ((const float4*)x)[o4];
  const float4 b4 = ((const float4*)bias)[tid];
  xv.x += b4.x; xv.y += b4.y; xv.z += b4.z; xv.w += b4.w;
  for (int k = 0; k < nsk; k++) {
    const float4 p = ((const float4*)part)[(size_t)k * ROWS * 192 + o4];
    xv.x += p.x; xv.y += p.y; xv.z += p.z; xv.w += p.w;
  }
  ((float4*)x)[o4] = xv;
  float sum = xv.x + xv.y + xv.z + xv.w;
  float sq = xv.x * xv.x + xv.y * xv.y + xv.z * xv.z + xv.w * xv.w;
#pragma unroll
  for (int off = 32; off > 0; off >>= 1) {
    sum += __shfl_xor(sum, off);
    sq  += __shfl_xor(sq, off);
  }
  __shared__ float red[6];
  const int wid = tid >> 6, lane = tid & 63;
  if (lane == 0) { red[wid] = sum; red[wid + 3] = sq; }
  __syncthreads();
  sum = red[0] + red[1] + red[2];
  sq  = red[3] + red[4] + red[5];
  const float mu = sum * (1.f / Dm);
  const float var = sq * (1.f / Dm) - mu * mu;
  const float rstd = rsqrtf(var + LN_EPS);
  const float4 w4 = ((const float4*)w)[tid];
  const float4 bb4 = ((const float4*)b)[tid];
  ushort4 o;
  o.x = f2bf((xv.x - mu) * rstd * w4.x + bb4.x);
  o.y = f2bf((xv.y - mu) * rstd * w4.y + bb4.y);
  o.z = f2bf((xv.z - mu) * rstd * w4.z + bb4.z);
  o.w = f2bf((xv.w - mu) * rstd * w4.w + bb4.w);
  ((ushort4*)out)[o4] = o;
}

// ---------------------------------------------------------------------------
// Weight converter fp32 -> bf16
// ---------------------------------------------------------------------------
__global__ __launch_bounds__(256) void convert_w(
    const float* __restrict__ s, ushort* __restrict__ d, int n4) {
  const int stride = gridDim.x * 256;
  for (int i = blockIdx.x * 256 + threadIdx.x; i < n4; i += stride) {
    const float4 v = ((const float4*)s)[i];
    ushort4 o;
    o.x = f2bf(v.x); o.y = f2bf(v.y); o.z = f2bf(v.z); o.w = f2bf(v.w);
    ((ushort4*)d)[i] = o;
  }
}

// ---------------------------------------------------------------------------
// bf16 MFMA GEMM (loop GEMMs) — unchanged R11.
// ---------------------------------------------------------------------------
#define EPI_QKV 0
#define EPI_PART 1
#define EPI_BIAS_GELU 2
#define EPI_NONE 3

template <int EPI>
__global__ __launch_bounds__(256) void gemm_mfma(
    const ushort* __restrict__ A, const ushort* __restrict__ B,
    const float* __restrict__ bias, void* __restrict__ Cv,
    void* __restrict__ Cv2, int Kloop, int Kstr, int Nloc, int ldC) {
  __shared__ char lds[32768];
  const int tid = threadIdx.x;
  const int l = tid & 63;
  const int wid = __builtin_amdgcn_readfirstlane(tid >> 6);
  const int wr = wid >> 1, wc = wid & 1;
  const int m0 = blockIdx.y * 128;
  const int n0 = blockIdx.x * 128;
  const int z = (EPI == EPI_PART) ? blockIdx.z : 0;
  if (EPI == EPI_PART) { A += (size_t)z * Kloop; B += (size_t)z * Kloop; }

  const int cperm = (((l & 3) ^ ((l >> 3) & 3)) * 8);
  const ushort* gA = A + (size_t)(m0 + wid * 32 + (l >> 2)) * Kstr + cperm;
  int rB = n0 + wid * 32 + (l >> 2);
  rB = min(rB, Nloc - 1);
  const ushort* gB = B + (size_t)rB * Kstr + cperm;

  const int rdSw = (l & 15) * 64 + (((l >> 4) ^ ((l >> 1) & 3)) * 16);
  const int aRd = wr * 4096 + rdSw;
  const int bRd = 8192 + wc * 4096 + rdSw;

  f32x4 acc[4][4] = {};
  const int nt = Kloop / 32;

  {
    const int lb = wid * 2048;
    GLL(gA, lds + lb);          GLL(gA + 16 * Kstr, lds + lb + 1024);
    GLL(gB, lds + 8192 + lb);   GLL(gB + 16 * Kstr, lds + 8192 + lb + 1024);
  }

  for (int t = 0; t < nt; ++t) {
    __syncthreads();
    if (t + 1 < nt) {
      const int base = ((t + 1) & 1) * 16384;
      const int lb = base + wid * 2048;
      const ushort* a = gA + (t + 1) * 32;
      const ushort* b = gB + (t + 1) * 32;
      GLL(a, lds + lb);         GLL(a + 16 * Kstr, lds + lb + 1024);
      GLL(b, lds + 8192 + lb);  GLL(b + 16 * Kstr, lds + 8192 + lb + 1024);
    }
    const int base = (t & 1) * 16384;
    bf16x8 av[4], bv[4];
#pragma unroll
    for (int i = 0; i < 4; ++i) {
      av[i] = *(const bf16x8*)(lds + base + aRd + i * 1024);
      bv[i] = *(const bf16x8*)(lds + base + bRd + i * 1024);
    }
#pragma unroll
    for (int i = 0; i < 4; ++i)
#pragma unroll
      for (int j = 0; j < 4; ++j)
        acc[i][j] = MF(av[i], bv[j], acc[i][j]);
  }

#pragma unroll
  for (int fm = 0; fm < 4; ++fm) {
    const int row0 = m0 + wr * 64 + fm * 16 + (l >> 4) * 4;
#pragma unroll
    for (int fn = 0; fn < 4; ++fn) {
      const int col = n0 + wc * 64 + fn * 16 + (l & 15);
      if (col >= Nloc) continue;
      float bi = 0.f;
      if (EPI == EPI_QKV || EPI == EPI_BIAS_GELU) bi = bias[col];
      if (EPI == EPI_QKV && col >= 2 * Dm) {
        const int hh = (col - 2 * Dm) >> 6, dd = col & 63;
        const int bI = row0 >> 10, t0 = row0 & (Tt - 1);
        ushort4 o4;
        o4.x = f2bf(acc[fm][fn][0] + bi);
        o4.y = f2bf(acc[fm][fn][1] + bi);
        o4.z = f2bf(acc[fm][fn][2] + bi);
        o4.w = f2bf(acc[fm][fn][3] + bi);
        *(ushort4*)((ushort*)Cv2 +
                    ((size_t)((bI * Hh + hh) * 64 + dd)) * Tt + t0) = o4;
        continue;
      }
#pragma unroll
      for (int r = 0; r < 4; ++r) {
        float v = acc[fm][fn][r] + bi;
        const size_t off = (size_t)(row0 + r) * ldC + col;
        if (EPI == EPI_BIAS_GELU) {
          v = 0.5f * v * (1.f + erff(v * 0.70710678118654752f));
          ((ushort*)Cv)[off] = f2bf(v);
        } else if (EPI == EPI_QKV) {
          ((ushort*)Cv)[off] = f2bf(v);
        } else if (EPI == EPI_PART) {
          ((float*)Cv)[(size_t)z * ROWS * ldC + off] = v;
        } else {
          ((float*)Cv)[off] = v;
        }
      }
    }
  }
}

// ---------------------------------------------------------------------------
// Head GEMM — 8-phase counted-vmcnt schedule (T3+T4+T5, m201-style port).
// 256x256 tile, BK=64, 512 thr / 8 waves (2M x 4N), per-wave 128x64.
// LDS 128KB: A[d][h] = (d*2+h)*16KB (d=tile&1, h=row-half), B at +64KB.
// Half-tile = 128 rows x 64 cols bf16 = 16KB = 2 GLL/thread.
// Swizzle: 8 chunks/row, slot = q ^ (r&7) both-sides (r&7 == s&7 for frags
// since row bases are mult of 8 -> 8 distinct bank starts, 2-way = free).
// Per iter (2 K-tiles t0,t1): 8 phases; phase = {reads, stage, barrier,
// lgkmcnt(0)+sched_barrier, setprio(1), 16 MFMA, setprio(0), [vmcnt], barrier}
// B-frags hoisted to phase 1/5 (frees B region after first phase).
// Staging ledger (iter i; t1=2i+1, t2=2i+2, t3=2i+3; guards t<12):
//   ph1: A0(t1)   ph2: A1(t1), B0(t2)   ph3: B1(t2)   ph4: vmcnt(4)
//   ph5: A0(t2)   ph6: A1(t2)           ph7: B0(t3)   ph8: B1(t3), vmcnt(4)
// vmcnt(4)@ph4 completes A/B(t1) (4 newer loads = B0/B1(t2)); vmcnt(4)@ph8
// completes A(t2)+older (4 newer = B0/B1(t3)). Tail i=5: vmcnt(0)@ph4.
// Prologue: B0/B1/A0/A1(0), B0/B1(1) staged; vmcnt(4) -> tile0 resident.
// ---------------------------------------------------------------------------
__global__ __launch_bounds__(512, 2) void gemm_head8(
    const ushort* __restrict__ A, const ushort* __restrict__ B,
    float* __restrict__ C) {
  __shared__ char lds[131072];
  const int tid = threadIdx.x;
  const int l = tid & 63;
  const int wid = __builtin_amdgcn_readfirstlane(tid >> 6);
  const int wm = wid >> 2, wn = wid & 3;
  const int s = l & 15, g = l >> 4;

  // XCD panel-major swizzle (197 panels x 8 m-rows)
  const int bid = blockIdx.x;
  const int swz = (bid & 7) * 197 + (bid >> 3);
  const int pan = swz >> 3, mrw = swz & 7;
  const int m0 = mrw * 256;
  const int n0 = pan * 256;

  // staging addressing: thread covers chunks c = tid (rows 0-63) and
  // c = tid+512 (rows 64-127) of each half-tile; global chunk pre-swizzled.
  const int r0 = tid >> 3;
  const int q0 = (tid & 7) ^ (r0 & 7);
  const ushort* pA0 = A + (size_t)(m0 + r0) * Dm + q0 * 8;
  const ushort* pA1 = pA0 + (size_t)64 * Dm;
  const ushort* pB[2][2];
  pB[0][0] = B + (size_t)min(n0 + r0, Vv - 1) * Dm + q0 * 8;
  pB[0][1] = B + (size_t)min(n0 + 64 + r0, Vv - 1) * Dm + q0 * 8;
  pB[1][0] = B + (size_t)min(n0 + 128 + r0, Vv - 1) * Dm + q0 * 8;
  pB[1][1] = B + (size_t)min(n0 + 192 + r0, Vv - 1) * Dm + q0 * 8;

#define STG_A(t, h) do { if ((t) < 12) {                                     \
    char* _d = lds + ((((t) & 1) * 2 + (h)) * 16384);                        \
    GLL(pA0 + (size_t)(h) * 98304 + (t) * 64, _d + tid * 16);                \
    GLL(pA1 + (size_t)(h) * 98304 + (t) * 64, _d + 8192 + tid * 16);         \
  }} while (0)
#define STG_B(t, h) do { if ((t) < 12) {                                     \
    char* _d = lds + 65536 + ((((t) & 1) * 2 + (h)) * 16384);                \
    GLL(pB[h][0] + (t) * 64, _d + tid * 16);                                 \
    GLL(pB[h][1] + (t) * 64, _d + 8192 + tid * 16);                          \
  }} while (0)

  // fragment read offsets (dbuf base added at use)
  const int aK0 = ((0 * 4 + g) ^ (s & 7)) * 16;
  const int aK1 = ((1 * 4 + g) ^ (s & 7)) * 16;
  const int aBase = wm * 16384 + s * 128;
  const int bBase = 65536 + (wn >> 1) * 16384 + (wn & 1) * 8192 + s * 128;

  f32x4 acc[8][4] = {};
  bf16x8 bv[4][2];

#define PH(t, p, STAGES, VMC)                                                \
  {                                                                          \
    const int cur = ((t) & 1) * 32768;                                       \
    if ((p) == 1) {                                                          \
      _Pragma("unroll")                                                      \
      for (int fn = 0; fn < 4; fn++) {                                       \
        bv[fn][0] = *(const bf16x8*)(lds + cur + bBase + fn * 2048 + aK0);   \
        bv[fn][1] = *(const bf16x8*)(lds + cur + bBase + fn * 2048 + aK1);   \
      }                                                                      \
    }                                                                        \
    bf16x8 a00 = *(const bf16x8*)(lds + cur + aBase + (2*(p)-2)*2048 + aK0); \
    bf16x8 a01 = *(const bf16x8*)(lds + cur + aBase + (2*(p)-2)*2048 + aK1); \
    bf16x8 a10 = *(const bf16x8*)(lds + cur + aBase + (2*(p)-1)*2048 + aK0); \
    bf16x8 a11 = *(const bf16x8*)(lds + cur + aBase + (2*(p)-1)*2048 + aK1); \
    STAGES;                                                                  \
    __builtin_amdgcn_s_barrier();                                            \
    asm volatile("s_waitcnt lgkmcnt(0)" ::: "memory");                       \
    __builtin_amdgcn_sched_barrier(0);                                       \
    __builtin_amdgcn_s_setprio(1);                                           \
    _Pragma("unroll")                                                        \
    for (int fn = 0; fn < 4; fn++) {                                         \
      acc[2*(p)-2][fn] = MF(a00, bv[fn][0], acc[2*(p)-2][fn]);               \
      acc[2*(p)-2][fn] = MF(a01, bv[fn][1], acc[2*(p)-2][fn]);               \
      acc[2*(p)-1][fn] = MF(a10, bv[fn][0], acc[2*(p)-1][fn]);               \
      acc[2*(p)-1][fn] = MF(a11, bv[fn][1], acc[2*(p)-1][fn]);               \
    }                                                                        \
    __builtin_amdgcn_s_setprio(0);                                           \
    VMC;                                                                     \
    __builtin_amdgcn_s_barrier();                                            \
  }

  // prologue
  STG_B(0, 0); STG_B(0, 1); STG_A(0, 0); STG_A(0, 1); STG_B(1, 0); STG_B(1, 1);
  asm volatile("s_waitcnt vmcnt(4)" ::: "memory");
  __builtin_amdgcn_s_barrier();

#pragma unroll 1
  for (int i = 0; i < 6; ++i) {
    const int t0 = 2 * i, t1 = 2 * i + 1, t2 = 2 * i + 2, t3 = 2 * i + 3;
    PH(t0, 1, { STG_A(t1, 0); }, {});
    PH(t0, 2, { STG_A(t1, 1); STG_B(t2, 0); }, {});
    PH(t0, 3, { STG_B(t2, 1); }, {});
    if (i < 5) {
      PH(t0, 4, {}, { asm volatile("s_waitcnt vmcnt(4)" ::: "memory"); });
    } else {
      PH(t0, 4, {}, { asm volatile("s_waitcnt vmcnt(0)" ::: "memory"); });
    }
    PH(t1, 1, { STG_A(t2, 0); }, {});
    PH(t1, 2, { STG_A(t2, 1); }, {});
    PH(t1, 3, { STG_B(t3, 0); }, {});
    if (i < 5) {
      PH(t1, 4, { STG_B(t3, 1); },
         { asm volatile("s_waitcnt vmcnt(4)" ::: "memory"); });
    } else {
      PH(t1, 4, {}, {});
    }
  }

  // epilogue: C/D layout col = s (B-row), row = g*4 + r (A-row)
#pragma unroll
  for (int fm = 0; fm < 8; ++fm) {
    const int row0 = m0 + wm * 128 + fm * 16 + g * 4;
#pragma unroll
    for (int fn = 0; fn < 4; ++fn) {
      const int col = n0 + wn * 64 + fn * 16 + s;
      if (col >= Vv) continue;
#pragma unroll
      for (int r = 0; r < 4; ++r)
        C[(size_t)(row0 + r) * Vv + col] = acc[fm][fn][r];
    }
  }
#undef PH
#undef STG_A
#undef STG_B
}

// ---------------------------------------------------------------------------
// MFMA flash attention (R8, unchanged).
// ---------------------------------------------------------------------------
__global__ __launch_bounds__(128) void attn_mfma(
    const ushort* __restrict__ qkv, const ushort* __restrict__ vTg,
    ushort* __restrict__ y) {
  __shared__ char lds[36864];
  const int tid = threadIdx.x;
  const int l = tid & 63;
  const int w = tid >> 6;
  const int s = l & 15, g = l >> 4;
  const int bq = gridDim.x - 1 - blockIdx.x;
  const int h = blockIdx.y, b = blockIdx.z;
  const int bh = b * Hh + h;

  const int qrow = bq * 32 + w * 16 + s;
  const ushort* qp = qkv + (size_t)(b * Tt + qrow) * 2304 + h * 64 + g * 8;
  const bf16x8 aq0 = *(const bf16x8*)qp;
  const bf16x8 aq1 = *(const bf16x8*)(qp + 32);

  size_t gofs[8];
#pragma unroll
  for (int i = 0; i < 8; i++) {
    const int c = tid + i * 128;
    if (i < 4) {
      const int kr = c >> 3;
      gofs[i] = (size_t)(b * Tt + kr) * 2304 + Dm + h * 64 + ((c & 7) ^ (kr & 7)) * 8;
    } else {
      const int cv = c - 512;
      const int vr = cv >> 3;
      gofs[i] = (size_t)(bh * 64 + vr) * Tt + ((cv & 7) ^ (vr & 7)) * 8;
    }
  }

#define ASTAGE(kt, base)                                                     \
  do {                                                                       \
    _Pragma("unroll")                                                        \
    for (int i = 0; i < 8; i++) {                                            \
      const ushort* p = (i < 4) ? (qkv + gofs[i] + (size_t)(kt) * 147456)    \
                                : (vTg + gofs[i] + (kt) * 64);               \
      GLL(p, lds + (base) + tid * 16 + i * 2048);                            \
    }                                                                        \
  } while (0)

  f32x4 oc[4] = {};
  float mrun[4], lrun[4];
#pragma unroll
  for (int r = 0; r < 4; r++) { mrun[r] = -INFINITY; lrun[r] = 0.f; }

  const int pB = 32768 + w * 2048;
  const int kSw = (s & 7);
  const int nkt = (bq >> 1) + 1;

  ASTAGE(0, 0);
  for (int kt = 0; kt < nkt; ++kt) {
    __syncthreads();
    if (kt + 1 < nkt) ASTAGE(kt + 1, ((kt + 1) & 1) * 16384);
    const int cur = (kt & 1) * 16384;

    f32x4 sc[4];
    __builtin_amdgcn_s_setprio(1);
#pragma unroll
    for (int jn = 0; jn < 4; jn++) {
      const int krow = cur + (jn * 16 + s) * 128;
      const bf16x8 bk0 = *(const bf16x8*)(lds + krow + ((g ^ kSw) * 16));
      const bf16x8 bk1 = *(const bf16x8*)(lds + krow + (((4 + g) ^ kSw) * 16));
      f32x4 z = {};
      z = MF(aq0, bk0, z);
      z = MF(aq1, bk1, z);
      sc[jn] = z;
    }
    __builtin_amdgcn_s_setprio(0);

    float cr[4];
    const bool diag = (kt == nkt - 1);
#pragma unroll
    for (int r = 0; r < 4; r++) {
      const int rowg = bq * 32 + w * 16 + g * 4 + r;
      float v[4];
#pragma unroll
      for (int jn = 0; jn < 4; jn++) {
        v[jn] = sc[jn][r] * 0.125f;
        if (diag && (kt * 64 + jn * 16 + s) > rowg) v[jn] = -INFINITY;
      }
      float mx = fmaxf(fmaxf(v[0], v[1]), fmaxf(v[2], v[3]));
      mx = fmaxf(mx, __shfl_xor(mx, 1));
      mx = fmaxf(mx, __shfl_xor(mx, 2));
      mx = fmaxf(mx, __shfl_xor(mx, 4));
      mx = fmaxf(mx, __shfl_xor(mx, 8));
      const float mnew = fmaxf(mrun[r], mx);
      const float corr = __expf(mrun[r] - mnew);
      mrun[r] = mnew;
      float ps = 0.f;
#pragma unroll
      for (int jn = 0; jn < 4; jn++) {
        const float p = __expf(v[jn] - mnew);
        ps += p;
        *(ushort*)(lds + pB + (g * 4 + r) * 128 +
                   (((2 * jn + (s >> 3)) ^ g) * 16) + (s & 7) * 2) = f2bf(p);
      }
      ps += __shfl_xor(ps, 1);
      ps += __shfl_xor(ps, 2);
      ps += __shfl_xor(ps, 4);
      ps += __shfl_xor(ps, 8);
      lrun[r] = lrun[r] * corr + ps;
      cr[r] = corr;
    }

    const float c01 = (s & 1) ? cr[1] : cr[0];
    const float c23 = (s & 1) ? cr[3] : cr[2];
    const float csel = (s & 2) ? c23 : c01;
    const float ccol = __shfl(csel, ((s >> 2) << 4) | s);
#pragma unroll
    for (int fm = 0; fm < 4; fm++) {
      oc[fm][0] *= ccol; oc[fm][1] *= ccol;
      oc[fm][2] *= ccol; oc[fm][3] *= ccol;
    }

    const bf16x8 bp0 = *(const bf16x8*)(lds + pB + s * 128 + ((g ^ (s >> 2)) * 16));
    const bf16x8 bp1 = *(const bf16x8*)(lds + pB + s * 128 + (((4 + g) ^ (s >> 2)) * 16));
    __builtin_amdgcn_s_setprio(1);
#pragma unroll
    for (int fm = 0; fm < 4; fm++) {
      const int vrow = cur + 8192 + (fm * 16 + s) * 128;
      const bf16x8 av0 = *(const bf16x8*)(lds + vrow + ((g ^ kSw) * 16));
      const bf16x8 av1 = *(const bf16x8*)(lds + vrow + (((4 + g) ^ kSw) * 16));
      oc[fm] = MF(av0, bp0, oc[fm]);
      oc[fm] = MF(av1, bp1, oc[fm]);
    }
    __builtin_amdgcn_s_setprio(0);
  }

  float li[4];
#pragma unroll
  for (int r = 0; r < 4; r++) li[r] = 1.f / lrun[r];
  const float l01 = (s & 1) ? li[1] : li[0];
  const float l23 = (s & 1) ? li[3] : li[2];
  const float lsel = (s & 2) ? l23 : l01;
  const float lcol = __shfl(lsel, ((s >> 2) << 4) | s);
  ushort* yp = y + (size_t)(b * Tt + qrow) * Dm + h * 64;
#pragma unroll
  for (int fm = 0; fm < 4; fm++) {
    ushort4 o4;
    o4.x = f2bf(oc[fm][0] * lcol);
    o4.y = f2bf(oc[fm][1] * lcol);
    o4.z = f2bf(oc[fm][2] * lcol);
    o4.w = f2bf(oc[fm][3] * lcol);
    *(ushort4*)(yp + fm * 16 + g * 4) = o4;
  }
}

// ---------------------------------------------------------------------------
extern "C" void kernel_launch(void* const* d_in, const int* in_sizes, int n_in,
                              void* d_out, int out_size, void* d_ws, size_t ws_size,
                              hipStream_t stream) {
  const int* idx = (const int*)d_in[0];
  const float* tok = (const float*)d_in[1];
  const float* pos = (const float*)d_in[2];
  const float* ln1w = (const float*)d_in[3];
  const float* ln1b = (const float*)d_in[4];
  const float* qkvw = (const float*)d_in[5];
  const float* qkvb = (const float*)d_in[6];
  const float* projw = (const float*)d_in[7];
  const float* projb = (const float*)d_in[8];
  const float* ln2w = (const float*)d_in[9];
  const float* ln2b = (const float*)d_in[10];
  const float* ff1w = (const float*)d_in[11];
  const float* ff1b = (const float*)d_in[12];
  const float* ff2w = (const float*)d_in[13];
  const float* ff2b = (const float*)d_in[14];
  const float* lnfw = (const float*)d_in[15];
  const float* lnfb = (const float*)d_in[16];
  const float* headw = (const float*)d_in[17];
  float* out = (float*)d_out;

  char* ws = (char*)d_ws;
  ushort* h    = (ushort*)ws;                    // [2048][768] bf16
  float*  x    = (float*)(ws + 3145728);         // [2048][768] fp32
  ushort* y    = (ushort*)(ws + 9437184);        // [2048][768] bf16
  ushort* qkv  = (ushort*)(ws + 12582912);       // [2048][2304] bf16
  ushort* vTg  = (ushort*)(ws + 22020096);       // [24][64][1024] bf16
  ushort* ff   = (ushort*)(ws + 25165824);       // [2048][4096] bf16
  ushort* wb   = (ushort*)(ws + 41943040);       // all weights bf16 (284.8MB)
  float* projPart = (float*)(ws + 326755840);    // 4 x 6.29MB
  float* ff2Part  = (float*)(ws + 351921664);    // 4 x 6.29MB

  const size_t oPROJ = (size_t)Ll * 3 * Dm * Dm;
  const size_t oFF1  = oPROJ + (size_t)Ll * Dm * Dm;
  const size_t oFF2  = oFF1 + (size_t)Ll * DFF * Dm;
  const size_t oHEAD = oFF2 + (size_t)Ll * Dm * DFF;

  convert_w<<<2048, 256, 0, stream>>>(qkvw, wb, (int)(oPROJ / 4));
  convert_w<<<2048, 256, 0, stream>>>(projw, wb + oPROJ, (int)((oFF1 - oPROJ) / 4));
  convert_w<<<2048, 256, 0, stream>>>(ff1w, wb + oFF1, (int)((oFF2 - oFF1) / 4));
  convert_w<<<2048, 256, 0, stream>>>(ff2w, wb + oFF2, (int)((oHEAD - oFF2) / 4));
  convert_w<<<2048, 256, 0, stream>>>(headw, wb + oHEAD, (int)((size_t)Vv * Dm / 4));

  embed_ln<<<ROWS, 256, 0, stream>>>(idx, tok, pos, ln1w, ln1b, x, h);

  for (int l = 0; l < Ll; l++) {
    gemm_mfma<EPI_QKV><<<dim3(18, 16), 256, 0, stream>>>(
        h, wb + (size_t)l * 3 * Dm * Dm, qkvb + l * 3 * Dm, qkv, vTg,
        Dm, Dm, 3 * Dm, 3 * Dm);
    attn_mfma<<<dim3(32, Hh, Bb), 128, 0, stream>>>(qkv, vTg, y);
    gemm_mfma<EPI_PART><<<dim3(6, 16, 4), 256, 0, stream>>>(
        y, wb + oPROJ + (size_t)l * Dm * Dm, nullptr, projPart, nullptr,
        Dm / 4, Dm, Dm, Dm);
    red_ln<<<ROWS, 192, 0, stream>>>(projPart, 4, projb + l * Dm, x,
                                     ln2w + l * Dm, ln2b + l * Dm, h);
    gemm_mfma<EPI_BIAS_GELU><<<dim3(32, 16), 256, 0, stream>>>(
        h, wb + oFF1 + (size_t)l * DFF * Dm, ff1b + l * DFF, ff, nullptr,
        Dm, Dm, DFF, DFF);
    gemm_mfma<EPI_PART><<<dim3(6, 16, 4), 256, 0, stream>>>(
        ff, wb + oFF2 + (size_t)l * Dm * DFF, nullptr, ff2Part, nullptr,
        DFF / 4, DFF, Dm, Dm);
    const float* nw = (l == Ll - 1) ? lnfw : ln1w + (l + 1) * Dm;
    const float* nb = (l == Ll - 1) ? lnfb : ln1b + (l + 1) * Dm;
    red_ln<<<ROWS, 192, 0, stream>>>(ff2Part, 4, ff2b + l * Dm, x, nw, nb, h);
  }

  gemm_head8<<<1576, 512, 0, stream>>>(h, wb + oHEAD, out);
}